// Round 2
// baseline (1866.541 us; speedup 1.0000x reference)
//
#include <hip/hip_runtime.h>

// ---------------- problem constants ----------------
#define NHEADS 8
#define CHD 32
#define CDIM 256
#define C3 768
#define NTOK 16384
#define MDET 100
#define TPB (NTOK + MDET)      // 16484
#define BATCH 4
#define ROWS (BATCH * TPB)     // 65936
#define DROWS (BATCH * MDET)   // 400
#define HH 128
#define WW 128
#define SCALE 0.17677669529663687f
#define SCH 32
#define FCH 32

// ---- bf16 helpers (manual, bit-level) ----
__device__ __forceinline__ float bf2f(unsigned short u) {
  union { unsigned int i; float f; } z; z.i = ((unsigned int)u) << 16; return z.f;
}
__device__ __forceinline__ unsigned short f2bf(float f) {
  union { float f; unsigned int i; } z; z.f = f;
  unsigned int i = z.i;
  unsigned int r = (i + 0x7FFFu + ((i >> 16) & 1u)) >> 16;
  return (unsigned short)r;
}

// ---- ws layout (byte offsets) ----
static const size_t B_KV     = 0;                                   // ushort [ROWS][512]
static const size_t B_XOUT   = B_KV + (size_t)ROWS * 512 * 2;       // ushort [ROWS][256]
static const size_t B_DETQ   = B_XOUT + (size_t)ROWS * 256 * 2;     // float [448][256]
static const size_t B_PM     = B_DETQ + (size_t)448 * 256 * 4;      // float [1024][32]
static const size_t B_PS     = B_PM + 1024 * 32 * 4;
static const size_t B_FPART  = B_PS + 1024 * 32 * 4;                // float [1024][1024]
static const size_t B_FACTOR = B_FPART + (size_t)1024 * 1024 * 4;   // float [32][1024]
static const size_t B_LSE    = B_FACTOR + 32768 * 4;                // float [1024]
static const size_t B_END    = B_LSE + 1024 * 4;

// ---------------- K|V GEMM: gathered rows (x|det) @ qkv_w[:,256:768] --------
__global__ __launch_bounds__(256)
void qkv_kv_gemm(const float* __restrict__ x, const float* __restrict__ det,
                 const float* __restrict__ W, const float* __restrict__ bias,
                 unsigned short* __restrict__ kv) {
  const int row0 = blockIdx.x * 64;
  const int col0 = blockIdx.y * 64;          // 0..448 step 64 (512 cols)
  const int tid = threadIdx.x;
  const int tx = tid & 15, ty = tid >> 4;
  __shared__ float As[16][65];
  __shared__ float Bs[16][64];
  float acc[4][4] = {};

  const int lr = tid >> 2;
  const int lk = (tid & 3) * 4;
  const int grow = row0 + lr;
  const float* aptr = nullptr;
  if (grow < ROWS) {
    int b = grow / TPB, t = grow - b * TPB;
    aptr = (t < NTOK) ? (x + (size_t)(b * NTOK + t) * CDIM)
                      : (det + (size_t)(b * MDET + (t - NTOK)) * CDIM);
  }
  const int bkr = tid >> 4;
  const int bkc = (tid & 15) * 4;

  for (int kt = 0; kt < CDIM; kt += 16) {
    float4 av = make_float4(0.f, 0.f, 0.f, 0.f);
    if (aptr) av = *(const float4*)(aptr + kt + lk);
    As[lk + 0][lr] = av.x; As[lk + 1][lr] = av.y;
    As[lk + 2][lr] = av.z; As[lk + 3][lr] = av.w;
    float4 bv = *(const float4*)(W + (size_t)(kt + bkr) * C3 + CDIM + col0 + bkc);
    *(float4*)&Bs[bkr][bkc] = bv;
    __syncthreads();
#pragma unroll
    for (int kk = 0; kk < 16; ++kk) {
      float a[4], bb[4];
#pragma unroll
      for (int j = 0; j < 4; ++j) a[j] = As[kk][ty * 4 + j];
#pragma unroll
      for (int j = 0; j < 4; ++j) bb[j] = Bs[kk][tx * 4 + j];
#pragma unroll
      for (int i = 0; i < 4; ++i)
#pragma unroll
        for (int j = 0; j < 4; ++j) acc[i][j] += a[i] * bb[j];
    }
    __syncthreads();
  }
#pragma unroll
  for (int i = 0; i < 4; ++i) {
    int r = row0 + ty * 4 + i;
    if (r >= ROWS) continue;
    unsigned short* orow = kv + (size_t)r * 512 + col0 + tx * 4;
#pragma unroll
    for (int j = 0; j < 4; ++j)
      orow[j] = f2bf(acc[i][j] + bias[CDIM + col0 + tx * 4 + j]);
  }
}

// ---------------- det-q GEMM: det rows @ qkv_w[:,0:256] ---------------------
__global__ __launch_bounds__(256)
void detq_gemm(const float* __restrict__ det, const float* __restrict__ W,
               const float* __restrict__ bias, float* __restrict__ detq) {
  const int row0 = blockIdx.x * 64;
  const int col0 = blockIdx.y * 64;
  const int tid = threadIdx.x;
  const int tx = tid & 15, ty = tid >> 4;
  __shared__ float As[16][65];
  __shared__ float Bs[16][64];
  float acc[4][4] = {};

  const int lr = tid >> 2;
  const int lk = (tid & 3) * 4;
  const int grow = row0 + lr;
  const float* aptr = (grow < DROWS) ? (det + (size_t)grow * CDIM) : nullptr;
  const int bkr = tid >> 4;
  const int bkc = (tid & 15) * 4;

  for (int kt = 0; kt < CDIM; kt += 16) {
    float4 av = make_float4(0.f, 0.f, 0.f, 0.f);
    if (aptr) av = *(const float4*)(aptr + kt + lk);
    As[lk + 0][lr] = av.x; As[lk + 1][lr] = av.y;
    As[lk + 2][lr] = av.z; As[lk + 3][lr] = av.w;
    float4 bv = *(const float4*)(W + (size_t)(kt + bkr) * C3 + col0 + bkc);
    *(float4*)&Bs[bkr][bkc] = bv;
    __syncthreads();
#pragma unroll
    for (int kk = 0; kk < 16; ++kk) {
      float a[4], bb[4];
#pragma unroll
      for (int j = 0; j < 4; ++j) a[j] = As[kk][ty * 4 + j];
#pragma unroll
      for (int j = 0; j < 4; ++j) bb[j] = Bs[kk][tx * 4 + j];
#pragma unroll
      for (int i = 0; i < 4; ++i)
#pragma unroll
        for (int j = 0; j < 4; ++j) acc[i][j] += a[i] * bb[j];
    }
    __syncthreads();
  }
#pragma unroll
  for (int i = 0; i < 4; ++i) {
    int r = row0 + ty * 4 + i;
    if (r >= DROWS) continue;
    float* orow = detq + (size_t)r * CDIM + col0 + tx * 4;
#pragma unroll
    for (int j = 0; j < 4; ++j) orow[j] = acc[i][j] + bias[col0 + tx * 4 + j];
  }
}

// ---------------- softmax stats over tokens, per (b,h,c) --------------------
__global__ __launch_bounds__(256)
void kstats(const unsigned short* __restrict__ kv, float* __restrict__ pm,
            float* __restrict__ ps) {
  const int bid = blockIdx.x;
  const int chunk = bid & (SCH - 1);
  const int h = (bid / SCH) & 7;
  const int b = bid / (SCH * 8);
  const int tid = threadIdx.x;
  const int c = tid & 31, sub = tid >> 5;
  const size_t base = (size_t)b * TPB * 512 + h * CHD + c;
  const int t0 = chunk * (NTOK / SCH);
  float m = -1e30f, s = 0.f;
  for (int i = sub; i < NTOK / SCH; i += 8) {
    float k = bf2f(kv[base + (size_t)(t0 + i) * 512]);
    float nm = fmaxf(m, k);
    s = s * __expf(m - nm) + __expf(k - nm);
    m = nm;
  }
  __shared__ float sm[8][32], ss[8][32];
  sm[sub][c] = m; ss[sub][c] = s;
  __syncthreads();
  if (sub == 0) {
    for (int j = 1; j < 8; ++j) {
      float m2 = sm[j][c], s2 = ss[j][c];
      float nm = fmaxf(m, m2);
      s = s * __expf(m - nm) + s2 * __expf(m2 - nm);
      m = nm;
    }
    pm[bid * 32 + c] = m;
    ps[bid * 32 + c] = s;
  }
}

__global__ void kmerge(const float* __restrict__ pm, const float* __restrict__ ps,
                       float* __restrict__ lse) {
  int g = blockIdx.x * blockDim.x + threadIdx.x;
  if (g >= BATCH * 8 * 32) return;
  int c = g & 31, bh = g >> 5;
  float m = -1e30f, s = 0.f;
  for (int ch = 0; ch < SCH; ++ch) {
    int bid = bh * SCH + ch;
    float m2 = pm[bid * 32 + c], s2 = ps[bid * 32 + c];
    float nm = fmaxf(m, m2);
    s = s * __expf(m - nm) + s2 * __expf(m2 - nm);
    m = nm;
  }
  lse[g] = m + logf(s);
}

// ---------------- factor = ksoftmax^T @ V (split-K over tokens) -------------
__global__ __launch_bounds__(256)
void kfactor(const unsigned short* __restrict__ kv, const float* __restrict__ lse,
             float* __restrict__ fpart) {
  const int bid = blockIdx.x;
  const int chunk = bid & (FCH - 1);
  const int h = (bid / FCH) & 7;
  const int b = bid / (FCH * 8);
  const int tid = threadIdx.x;
  const int c = tid & 31;
  const int d0 = (tid >> 5) * 4;
  const float lse_c = lse[(b * 8 + h) * 32 + c];
  __shared__ float wsm[64][32];
  __shared__ float vsm[64][33];
  float a0 = 0.f, a1 = 0.f, a2 = 0.f, a3 = 0.f;
  const int t0 = chunk * (NTOK / FCH);
  const size_t rowb = (size_t)b * TPB;
  for (int st = 0; st < (NTOK / FCH) / 64; ++st) {
    int tb = t0 + st * 64;
#pragma unroll
    for (int i = 0; i < 8; ++i) {
      int flat = tid + i * 256;
      int tt = flat >> 5;
      int cc = flat & 31;
      size_t a = (rowb + tb + tt) * (size_t)512 + h * CHD + cc;
      wsm[tt][cc] = __expf(bf2f(kv[a]) - lse_c);
      vsm[tt][cc] = bf2f(kv[a + 256]);
    }
    __syncthreads();
#pragma unroll 4
    for (int tt = 0; tt < 64; ++tt) {
      float w = wsm[tt][c];
      a0 += w * vsm[tt][d0 + 0];
      a1 += w * vsm[tt][d0 + 1];
      a2 += w * vsm[tt][d0 + 2];
      a3 += w * vsm[tt][d0 + 3];
    }
    __syncthreads();
  }
  float* fp = fpart + ((size_t)bid * 32 + c) * 32 + d0;
  fp[0] = a0; fp[1] = a1; fp[2] = a2; fp[3] = a3;
}

__global__ void fmerge(const float* __restrict__ fpart, float* __restrict__ factor) {
  int o = blockIdx.x * 256 + threadIdx.x;
  if (o >= BATCH * 8 * CHD * CHD) return;
  int cd = o & 1023, bh = o >> 10;
  float s = 0.f;
  for (int ch = 0; ch < FCH; ++ch)
    s += fpart[((size_t)(bh * FCH + ch) << 10) + cd];
  factor[o] = s;
}

// ---------------- fused: recompute q + factor_att + CRPE + assemble ---------
template <int K>
__device__ __forceinline__ void patch_tail(
    const float* __restrict__ wk, const float* __restrict__ bk, int widx,
    const unsigned short* __restrict__ vbase, const float* __restrict__ fcol,
    const float (*q_s)[260], int tid, int h, int y, int x0,
    unsigned short* __restrict__ xo) {
  float w[K * K];
#pragma unroll
  for (int i = 0; i < K * K; ++i) w[i] = wk[widx * K * K + i];
  const float bias = bk[widx];
  float freg[32];
#pragma unroll
  for (int cc = 0; cc < 32; ++cc) freg[cc] = fcol[cc * 32];
  for (int t = 0; t < 64; ++t) {
    float fa = 0.f;
#pragma unroll
    for (int cc = 0; cc < 32; ++cc) fa += q_s[t][h * 32 + cc] * freg[cc];
    float o = bias;
    const int xx0 = x0 + t;
#pragma unroll
    for (int dy = 0; dy < K; ++dy) {
      const int yy = y + dy - K / 2;
      if (yy < 0 || yy >= HH) continue;
#pragma unroll
      for (int dx = 0; dx < K; ++dx) {
        const int xx = xx0 + dx - K / 2;
        float vv = (xx >= 0 && xx < WW)
                       ? bf2f(vbase[(size_t)(yy * WW + xx) * 512])
                       : 0.f;
        o += w[dy * K + dx] * vv;
      }
    }
    const float res = SCALE * fa + q_s[t][tid] * o;
    xo[(size_t)t * CDIM + tid] = f2bf(res);
  }
}

__global__ __launch_bounds__(256)
void kpatch_fused(const float* __restrict__ x, const float* __restrict__ W,
                  const float* __restrict__ qb, const unsigned short* __restrict__ kv,
                  const float* __restrict__ factor,
                  const float* __restrict__ w3, const float* __restrict__ b3,
                  const float* __restrict__ w5, const float* __restrict__ b5,
                  const float* __restrict__ w7, const float* __restrict__ b7,
                  unsigned short* __restrict__ xout) {
  const int bid = blockIdx.x;          // 0..1023
  const int b = bid >> 8;
  const int n0 = (bid & 255) * 64;
  const int y = n0 >> 7, x0 = n0 & 127;
  const int tid = threadIdx.x;

  __shared__ float As[16][65];
  __shared__ float Bs[16][64];
  __shared__ float q_s[64][260];

  const int tx = tid & 15, ty = tid >> 4;
  const int lr = tid >> 2;
  const int lk = (tid & 3) * 4;
  const float* xrow = x + ((size_t)b * NTOK + n0 + lr) * CDIM;
  const int bkr = tid >> 4;
  const int bkc = (tid & 15) * 4;

  for (int ct = 0; ct < 4; ++ct) {
    float acc[4][4] = {};
    for (int kt = 0; kt < CDIM; kt += 16) {
      float4 av = *(const float4*)(xrow + kt + lk);
      As[lk + 0][lr] = av.x; As[lk + 1][lr] = av.y;
      As[lk + 2][lr] = av.z; As[lk + 3][lr] = av.w;
      float4 bv = *(const float4*)(W + (size_t)(kt + bkr) * C3 + ct * 64 + bkc);
      *(float4*)&Bs[bkr][bkc] = bv;
      __syncthreads();
#pragma unroll
      for (int kk = 0; kk < 16; ++kk) {
        float a[4], bb[4];
#pragma unroll
        for (int j = 0; j < 4; ++j) a[j] = As[kk][ty * 4 + j];
#pragma unroll
        for (int j = 0; j < 4; ++j) bb[j] = Bs[kk][tx * 4 + j];
#pragma unroll
        for (int i = 0; i < 4; ++i)
#pragma unroll
          for (int j = 0; j < 4; ++j) acc[i][j] += a[i] * bb[j];
      }
      __syncthreads();
    }
#pragma unroll
    for (int i = 0; i < 4; ++i)
#pragma unroll
      for (int j = 0; j < 4; ++j)
        q_s[ty * 4 + i][ct * 64 + tx * 4 + j] =
            acc[i][j] + qb[ct * 64 + tx * 4 + j];
    __syncthreads();
  }

  const int h = tid >> 5;
  const unsigned short* vbase = kv + (size_t)b * TPB * 512 + 256 + tid;
  const float* fcol = factor + (size_t)((b * 8 + h) * 32) * 32 + (tid & 31);
  unsigned short* xo = xout + ((size_t)b * TPB + n0) * CDIM;

  if (h < 2)      patch_tail<3>(w3, b3, tid,       vbase, fcol, q_s, tid, h, y, x0, xo);
  else if (h < 5) patch_tail<5>(w5, b5, tid - 64,  vbase, fcol, q_s, tid, h, y, x0, xo);
  else            patch_tail<7>(w7, b7, tid - 160, vbase, fcol, q_s, tid, h, y, x0, xo);
}

// ---------------- det branch: standard attention over 100 tokens ------------
__global__ __launch_bounds__(128)
void kdet(const unsigned short* __restrict__ kv, const float* __restrict__ detq,
          unsigned short* __restrict__ xout) {
  const int bid = blockIdx.x;   // b*8+h
  const int b = bid >> 3, h = bid & 7;
  const int tid = threadIdx.x;
  __shared__ float qd[100][32], kd[100][32], vd[100][32];
  __shared__ float pd[100][101];
  const size_t rb = ((size_t)b * TPB + NTOK) * 512;
  for (int flat = tid; flat < 100 * 32; flat += 128) {
    int t = flat >> 5, cc = flat & 31;
    size_t a = rb + (size_t)t * 512 + h * CHD + cc;
    qd[t][cc] = detq[(size_t)(b * MDET + t) * CDIM + h * CHD + cc];
    kd[t][cc] = bf2f(kv[a]);
    vd[t][cc] = bf2f(kv[a + 256]);
  }
  __syncthreads();
  const int r = tid;
  if (r < 100) {
    float mx = -1e30f;
    for (int j = 0; j < 100; ++j) {
      float s = 0.f;
#pragma unroll
      for (int cc = 0; cc < 32; ++cc) s += qd[r][cc] * kd[j][cc];
      s *= SCALE;
      pd[r][j] = s;
      mx = fmaxf(mx, s);
    }
    float sum = 0.f;
    for (int j = 0; j < 100; ++j) {
      float e = __expf(pd[r][j] - mx);
      pd[r][j] = e;
      sum += e;
    }
    float inv = 1.f / sum;
    for (int d = 0; d < 32; ++d) {
      float o = 0.f;
      for (int j = 0; j < 100; ++j) o += pd[r][j] * vd[j][d];
      xout[((size_t)b * TPB + NTOK + r) * CDIM + h * CHD + d] = f2bf(o * inv);
    }
  }
}

// ---------------- proj GEMM (bf16 A) with split output write ----------------
__global__ __launch_bounds__(256)
void proj_gemm(const unsigned short* __restrict__ xin, const float* __restrict__ W,
               const float* __restrict__ bias, float* __restrict__ dout) {
  const int row0 = blockIdx.x * 64;
  const int col0 = blockIdx.y * 64;
  const int tid = threadIdx.x;
  const int tx = tid & 15, ty = tid >> 4;
  __shared__ float As[16][65];
  __shared__ float Bs[16][64];
  float acc[4][4] = {};

  const int lr = tid >> 2;
  const int lk = (tid & 3) * 4;
  const int grow = row0 + lr;
  const unsigned short* aptr = (grow < ROWS) ? (xin + (size_t)grow * CDIM) : nullptr;
  const int bkr = tid >> 4;
  const int bkc = (tid & 15) * 4;

  for (int kt = 0; kt < CDIM; kt += 16) {
    if (aptr) {
      ushort4 av = *(const ushort4*)(aptr + kt + lk);
      As[lk + 0][lr] = bf2f(av.x); As[lk + 1][lr] = bf2f(av.y);
      As[lk + 2][lr] = bf2f(av.z); As[lk + 3][lr] = bf2f(av.w);
    } else {
      As[lk + 0][lr] = 0.f; As[lk + 1][lr] = 0.f;
      As[lk + 2][lr] = 0.f; As[lk + 3][lr] = 0.f;
    }
    float4 bv = *(const float4*)(W + (size_t)(kt + bkr) * CDIM + col0 + bkc);
    *(float4*)&Bs[bkr][bkc] = bv;
    __syncthreads();
#pragma unroll
    for (int kk = 0; kk < 16; ++kk) {
      float a[4], bb[4];
#pragma unroll
      for (int j = 0; j < 4; ++j) a[j] = As[kk][ty * 4 + j];
#pragma unroll
      for (int j = 0; j < 4; ++j) bb[j] = Bs[kk][tx * 4 + j];
#pragma unroll
      for (int i = 0; i < 4; ++i)
#pragma unroll
        for (int j = 0; j < 4; ++j) acc[i][j] += a[i] * bb[j];
    }
    __syncthreads();
  }
#pragma unroll
  for (int i = 0; i < 4; ++i) {
    int r = row0 + ty * 4 + i;
    if (r >= ROWS) continue;
    int b = r / TPB, t = r - b * TPB;
    float* dst;
    if (t < NTOK)
      dst = dout + ((size_t)b * NTOK + t) * CDIM + col0 + tx * 4;
    else
      dst = dout + (size_t)BATCH * NTOK * CDIM +
            ((size_t)b * MDET + (t - NTOK)) * CDIM + col0 + tx * 4;
#pragma unroll
    for (int j = 0; j < 4; ++j) dst[j] = acc[i][j] + bias[col0 + tx * 4 + j];
  }
}

// ---------------- launch ----------------------------------------------------
extern "C" void kernel_launch(void* const* d_in, const int* in_sizes, int n_in,
                              void* d_out, int out_size, void* d_ws, size_t ws_size,
                              hipStream_t stream) {
  if (ws_size < B_END) return;   // diagnostic: clean fail instead of OOB crash

  const float* x      = (const float*)d_in[0];
  const float* det    = (const float*)d_in[1];
  const float* qkv_w  = (const float*)d_in[4];
  const float* qkv_b  = (const float*)d_in[5];
  const float* proj_w = (const float*)d_in[6];
  const float* proj_b = (const float*)d_in[7];
  const float* w3     = (const float*)d_in[8];
  const float* b3     = (const float*)d_in[9];
  const float* w5     = (const float*)d_in[10];
  const float* b5     = (const float*)d_in[11];
  const float* w7     = (const float*)d_in[12];
  const float* b7     = (const float*)d_in[13];

  char* wsb = (char*)d_ws;
  unsigned short* kv   = (unsigned short*)(wsb + B_KV);
  unsigned short* xout = (unsigned short*)(wsb + B_XOUT);
  float* detq   = (float*)(wsb + B_DETQ);
  float* pm     = (float*)(wsb + B_PM);
  float* ps     = (float*)(wsb + B_PS);
  float* fpart  = (float*)(wsb + B_FPART);
  float* factor = (float*)(wsb + B_FACTOR);
  float* lse    = (float*)(wsb + B_LSE);
  float* out    = (float*)d_out;

  dim3 g1((ROWS + 63) / 64, 512 / 64);
  qkv_kv_gemm<<<g1, 256, 0, stream>>>(x, det, qkv_w, qkv_b, kv);

  dim3 gd((DROWS + 63) / 64, CDIM / 64);
  detq_gemm<<<gd, 256, 0, stream>>>(det, qkv_w, qkv_b, detq);

  kstats<<<BATCH * 8 * SCH, 256, 0, stream>>>(kv, pm, ps);
  kmerge<<<4, 256, 0, stream>>>(pm, ps, lse);
  kfactor<<<BATCH * 8 * FCH, 256, 0, stream>>>(kv, lse, fpart);
  fmerge<<<128, 256, 0, stream>>>(fpart, factor);

  kpatch_fused<<<BATCH * 256, 256, 0, stream>>>(x, qkv_w, qkv_b, kv, factor,
                                                w3, b3, w5, b5, w7, b7, xout);
  kdet<<<BATCH * 8, 128, 0, stream>>>(kv, detq, xout);

  dim3 g2((ROWS + 63) / 64, CDIM / 64);
  proj_gemm<<<g2, 256, 0, stream>>>(xout, proj_w, proj_b, out);
}

// Round 3
// 515.892 us; speedup vs baseline: 3.6181x; 3.6181x over previous
//
#include <hip/hip_runtime.h>

// ---------------- problem constants ----------------
#define NHEADS 8
#define CHD 32
#define CDIM 256
#define C3 768
#define NTOK 16384
#define MDET 100
#define TPB (NTOK + MDET)      // 16484
#define BATCH 4
#define ROWS (BATCH * TPB)     // 65936
#define HH 128
#define WW 128
#define SCALE 0.17677669529663687f
#define SCH 32
#define FCH 16

typedef unsigned short u16;
typedef __attribute__((ext_vector_type(8))) __bf16 bf16x8;
typedef __attribute__((ext_vector_type(4))) float f32x4;

__device__ __forceinline__ float bf2f(u16 u) {
  union { unsigned int i; float f; } z; z.i = ((unsigned int)u) << 16; return z.f;
}
__device__ __forceinline__ u16 f2bf(float f) {
  __bf16 h = (__bf16)f;
  return __builtin_bit_cast(unsigned short, h);
}

// ---- ws layout (byte offsets); total 104,296,448 B < proven 106.33 MB ----
static const size_t B_QX     = 0;                                  // u16 [ROWS][256] q, later xout
static const size_t B_KVB    = B_QX + (size_t)ROWS * 256 * 2;      // u16 [ROWS][512] k|v
static const size_t B_WQT    = B_KVB + (size_t)ROWS * 512 * 2;     // u16 [768][256]
static const size_t B_WPT    = B_WQT + (size_t)768 * 256 * 2;      // u16 [256][256]
static const size_t B_PM     = B_WPT + (size_t)256 * 256 * 2;      // f32 [1024][32]
static const size_t B_PS     = B_PM + 1024 * 32 * 4;
static const size_t B_FPART  = B_PS + 1024 * 32 * 4;               // f32 [512][1024]
static const size_t B_FACTOR = B_FPART + (size_t)512 * 1024 * 4;   // f32 [32][1024]
static const size_t B_LSE    = B_FACTOR + 32768 * 4;               // f32 [1024]
static const size_t B_END    = B_LSE + 1024 * 4;

// ---------------- weight convert+transpose: W[k][n] -> Wt bf16 [n][k] -------
__global__ __launch_bounds__(256)
void wconv(const float* __restrict__ qkv_w, const float* __restrict__ proj_w,
           u16* __restrict__ WqT, u16* __restrict__ WpT) {
  int o = blockIdx.x * 256 + threadIdx.x;
  if (o < 768 * 256) {
    int n = o >> 8, k = o & 255;
    WqT[o] = f2bf(qkv_w[(size_t)k * C3 + n]);
  } else {
    int p = o - 768 * 256;
    int n = p >> 8, k = p & 255;
    WpT[p] = f2bf(proj_w[(size_t)k * CDIM + n]);
  }
}

// ---------------- MFMA GEMM: (x|det) @ qkv_w -> q-plane + kv-plane bf16 -----
__global__ __launch_bounds__(256)
void gemm_qkv(const float* __restrict__ x, const float* __restrict__ det,
              const u16* __restrict__ WqT, const float* __restrict__ bias,
              u16* __restrict__ qx, u16* __restrict__ kv) {
  const int row0 = blockIdx.x * 128;
  const int col0 = blockIdx.y * 128;
  const int tid = threadIdx.x;
  const int lane = tid & 63;
  const int wid = tid >> 6;
  const int wm = (wid & 1) * 64;
  const int wn = (wid >> 1) * 64;
  const int m16 = lane & 15;
  const int kg8 = (lane >> 4) * 8;

  __shared__ u16 As[128][72];
  __shared__ u16 Bs[128][72];

  const int sr = tid >> 1;
  const int sk = (tid & 1) * 32;

  int grow = row0 + sr;
  int crow = grow < ROWS ? grow : ROWS - 1;
  int bb = crow / TPB, tt = crow - bb * TPB;
  const float* aptr = (tt < NTOK)
      ? x + (size_t)(bb * NTOK + tt) * CDIM
      : det + (size_t)(bb * MDET + (tt - NTOK)) * CDIM;
  const u16* bptr = WqT + (size_t)(col0 + sr) * CDIM;

  f32x4 acc[4][4];
#pragma unroll
  for (int ni = 0; ni < 4; ++ni) {
    float bv = bias[col0 + wn + ni * 16 + m16];
#pragma unroll
    for (int mi = 0; mi < 4; ++mi)
      acc[mi][ni] = (f32x4){bv, bv, bv, bv};
  }

  for (int k0 = 0; k0 < CDIM; k0 += 64) {
#pragma unroll
    for (int j = 0; j < 4; ++j) {
      float4 v0 = *(const float4*)(aptr + k0 + sk + j * 8);
      float4 v1 = *(const float4*)(aptr + k0 + sk + j * 8 + 4);
      ushort4 u0, u1;
      u0.x = f2bf(v0.x); u0.y = f2bf(v0.y); u0.z = f2bf(v0.z); u0.w = f2bf(v0.w);
      u1.x = f2bf(v1.x); u1.y = f2bf(v1.y); u1.z = f2bf(v1.z); u1.w = f2bf(v1.w);
      *(ushort4*)&As[sr][sk + j * 8] = u0;
      *(ushort4*)&As[sr][sk + j * 8 + 4] = u1;
      *(uint4*)&Bs[sr][sk + j * 8] = *(const uint4*)(bptr + k0 + sk + j * 8);
    }
    __syncthreads();
#pragma unroll
    for (int kk = 0; kk < 2; ++kk) {
      bf16x8 af[4], bfr[4];
#pragma unroll
      for (int mi = 0; mi < 4; ++mi)
        af[mi] = *(const bf16x8*)&As[wm + mi * 16 + m16][kk * 32 + kg8];
#pragma unroll
      for (int ni = 0; ni < 4; ++ni)
        bfr[ni] = *(const bf16x8*)&Bs[wn + ni * 16 + m16][kk * 32 + kg8];
#pragma unroll
      for (int mi = 0; mi < 4; ++mi)
#pragma unroll
        for (int ni = 0; ni < 4; ++ni)
          acc[mi][ni] = __builtin_amdgcn_mfma_f32_16x16x32_bf16(
              af[mi], bfr[ni], acc[mi][ni], 0, 0, 0);
    }
    __syncthreads();
  }

  // epilogue: cols <256 -> qx (stride 256); cols >=256 -> kv (stride 512)
  u16* obase; int ostride, ocol0;
  if (col0 < 256) { obase = qx; ostride = 256; ocol0 = col0; }
  else            { obase = kv; ostride = 512; ocol0 = col0 - 256; }
  const int rbase = (lane >> 4) * 4;
#pragma unroll
  for (int mi = 0; mi < 4; ++mi) {
#pragma unroll
    for (int ni = 0; ni < 4; ++ni) {
      int col = ocol0 + wn + ni * 16 + m16;
#pragma unroll
      for (int r = 0; r < 4; ++r) {
        int rr = row0 + wm + mi * 16 + rbase + r;
        if (rr < ROWS)
          obase[(size_t)rr * ostride + col] = f2bf(acc[mi][ni][r]);
      }
    }
  }
}

// ---------------- MFMA GEMM: xout(bf16) @ proj_w -> d_out fp32 (split) ------
__global__ __launch_bounds__(256)
void gemm_proj(const u16* __restrict__ xin, const u16* __restrict__ WpT,
               const float* __restrict__ bias, float* __restrict__ dout) {
  const int row0 = blockIdx.x * 128;
  const int col0 = blockIdx.y * 128;
  const int tid = threadIdx.x;
  const int lane = tid & 63;
  const int wid = tid >> 6;
  const int wm = (wid & 1) * 64;
  const int wn = (wid >> 1) * 64;
  const int m16 = lane & 15;
  const int kg8 = (lane >> 4) * 8;

  __shared__ u16 As[128][72];
  __shared__ u16 Bs[128][72];

  const int sr = tid >> 1;
  const int sk = (tid & 1) * 32;

  int grow = row0 + sr;
  int crow = grow < ROWS ? grow : ROWS - 1;
  const u16* aptr = xin + (size_t)crow * CDIM;
  const u16* bptr = WpT + (size_t)(col0 + sr) * CDIM;

  f32x4 acc[4][4];
#pragma unroll
  for (int ni = 0; ni < 4; ++ni) {
    float bv = bias[col0 + wn + ni * 16 + m16];
#pragma unroll
    for (int mi = 0; mi < 4; ++mi)
      acc[mi][ni] = (f32x4){bv, bv, bv, bv};
  }

  for (int k0 = 0; k0 < CDIM; k0 += 64) {
#pragma unroll
    for (int j = 0; j < 4; ++j) {
      *(uint4*)&As[sr][sk + j * 8] = *(const uint4*)(aptr + k0 + sk + j * 8);
      *(uint4*)&Bs[sr][sk + j * 8] = *(const uint4*)(bptr + k0 + sk + j * 8);
    }
    __syncthreads();
#pragma unroll
    for (int kk = 0; kk < 2; ++kk) {
      bf16x8 af[4], bfr[4];
#pragma unroll
      for (int mi = 0; mi < 4; ++mi)
        af[mi] = *(const bf16x8*)&As[wm + mi * 16 + m16][kk * 32 + kg8];
#pragma unroll
      for (int ni = 0; ni < 4; ++ni)
        bfr[ni] = *(const bf16x8*)&Bs[wn + ni * 16 + m16][kk * 32 + kg8];
#pragma unroll
      for (int mi = 0; mi < 4; ++mi)
#pragma unroll
        for (int ni = 0; ni < 4; ++ni)
          acc[mi][ni] = __builtin_amdgcn_mfma_f32_16x16x32_bf16(
              af[mi], bfr[ni], acc[mi][ni], 0, 0, 0);
    }
    __syncthreads();
  }

  const int rbase = (lane >> 4) * 4;
#pragma unroll
  for (int mi = 0; mi < 4; ++mi) {
#pragma unroll
    for (int r = 0; r < 4; ++r) {
      int rr = row0 + wm + mi * 16 + rbase + r;
      if (rr >= ROWS) continue;
      int b = rr / TPB, t = rr - b * TPB;
      float* dst = (t < NTOK)
          ? dout + ((size_t)b * NTOK + t) * CDIM
          : dout + (size_t)BATCH * NTOK * CDIM + ((size_t)b * MDET + (t - NTOK)) * CDIM;
#pragma unroll
      for (int ni = 0; ni < 4; ++ni)
        dst[col0 + wn + ni * 16 + m16] = acc[mi][ni][r];
    }
  }
}

// ---------------- softmax stats over tokens, per (b,h,c) --------------------
__global__ __launch_bounds__(256)
void kstats(const u16* __restrict__ kv, float* __restrict__ pm,
            float* __restrict__ ps) {
  const int bid = blockIdx.x;
  const int chunk = bid & (SCH - 1);
  const int h = (bid / SCH) & 7;
  const int b = bid / (SCH * 8);
  const int tid = threadIdx.x;
  const int c = tid & 31, sub = tid >> 5;
  const size_t base = (size_t)b * TPB * 512 + h * CHD + c;
  const int t0 = chunk * (NTOK / SCH);
  float m = -1e30f, s = 0.f;
  for (int i = sub; i < NTOK / SCH; i += 8) {
    float k = bf2f(kv[base + (size_t)(t0 + i) * 512]);
    float nm = fmaxf(m, k);
    s = s * __expf(m - nm) + __expf(k - nm);
    m = nm;
  }
  __shared__ float sm[8][32], ss[8][32];
  sm[sub][c] = m; ss[sub][c] = s;
  __syncthreads();
  if (sub == 0) {
    for (int j = 1; j < 8; ++j) {
      float m2 = sm[j][c], s2 = ss[j][c];
      float nm = fmaxf(m, m2);
      s = s * __expf(m - nm) + s2 * __expf(m2 - nm);
      m = nm;
    }
    pm[bid * 32 + c] = m;
    ps[bid * 32 + c] = s;
  }
}

__global__ void kmerge(const float* __restrict__ pm, const float* __restrict__ ps,
                       float* __restrict__ lse) {
  int g = blockIdx.x * blockDim.x + threadIdx.x;
  if (g >= BATCH * 8 * 32) return;
  int c = g & 31, bh = g >> 5;
  float m = -1e30f, s = 0.f;
  for (int ch = 0; ch < SCH; ++ch) {
    int bid = bh * SCH + ch;
    float m2 = pm[bid * 32 + c], s2 = ps[bid * 32 + c];
    float nm = fmaxf(m, m2);
    s = s * __expf(m - nm) + s2 * __expf(m2 - nm);
    m = nm;
  }
  lse[g] = m + logf(s);
}

// ---------------- factor = ksoftmax^T @ V (split-K over tokens) -------------
__global__ __launch_bounds__(256)
void kfactor(const u16* __restrict__ kv, const float* __restrict__ lse,
             float* __restrict__ fpart) {
  const int bid = blockIdx.x;               // (b*8+h)*FCH + chunk
  const int chunk = bid & (FCH - 1);
  const int h = (bid / FCH) & 7;
  const int b = bid / (FCH * 8);
  const int tid = threadIdx.x;
  const int c = tid & 31;
  const int d0 = (tid >> 5) * 4;
  const float lse_c = lse[(b * 8 + h) * 32 + c];
  __shared__ float wsm[64][32];
  __shared__ float vsm[64][33];
  float a0 = 0.f, a1 = 0.f, a2 = 0.f, a3 = 0.f;
  const int t0 = chunk * (NTOK / FCH);
  const size_t rowb = (size_t)b * TPB;
  for (int st = 0; st < (NTOK / FCH) / 64; ++st) {
    int tb = t0 + st * 64;
#pragma unroll
    for (int i = 0; i < 8; ++i) {
      int flat = tid + i * 256;
      int tt = flat >> 5;
      int cc = flat & 31;
      size_t a = (rowb + tb + tt) * (size_t)512 + h * CHD + cc;
      wsm[tt][cc] = __expf(bf2f(kv[a]) - lse_c);
      vsm[tt][cc] = bf2f(kv[a + 256]);
    }
    __syncthreads();
#pragma unroll 4
    for (int tt = 0; tt < 64; ++tt) {
      float w = wsm[tt][c];
      a0 += w * vsm[tt][d0 + 0];
      a1 += w * vsm[tt][d0 + 1];
      a2 += w * vsm[tt][d0 + 2];
      a3 += w * vsm[tt][d0 + 3];
    }
    __syncthreads();
  }
  float* fp = fpart + ((size_t)bid * 32 + c) * 32 + d0;
  fp[0] = a0; fp[1] = a1; fp[2] = a2; fp[3] = a3;
}

__global__ void fmerge(const float* __restrict__ fpart, float* __restrict__ factor) {
  int o = blockIdx.x * 256 + threadIdx.x;
  if (o >= BATCH * 8 * CHD * CHD) return;
  int cd = o & 1023, bh = o >> 10;
  float s = 0.f;
  for (int ch = 0; ch < FCH; ++ch)
    s += fpart[((size_t)(bh * FCH + ch) << 10) + cd];
  factor[o] = s;
}

// ---------------- patch: tiled conv + factor_att + assemble -----------------
template <int K>
__device__ __forceinline__ void conv_tail(
    const float* __restrict__ wp, float wb,
    const u16 (&vt)[22][22][32], const u16 (&qt)[256][32],
    const float (&freg)[32], int c, int pg, size_t obase,
    u16* __restrict__ xo) {
  float w[K * K];
#pragma unroll
  for (int i = 0; i < K * K; ++i) w[i] = wp[i];
  for (int i = 0; i < 32; ++i) {
    const int pos = pg * 32 + i;
    const int sy = pos >> 4, sx = pos & 15;
    float fa = 0.f;
#pragma unroll
    for (int cc = 0; cc < 32; ++cc) fa += bf2f(qt[pos][cc]) * freg[cc];
    float o = wb;
#pragma unroll
    for (int dy = 0; dy < K; ++dy)
#pragma unroll
      for (int dx = 0; dx < K; ++dx)
        o += w[dy * K + dx] * bf2f(vt[sy + 3 + dy - K / 2][sx + 3 + dx - K / 2][c]);
    const float res = SCALE * fa + bf2f(qt[pos][c]) * o;
    xo[obase + (size_t)((sy << 7) + sx) * CDIM] = f2bf(res);
  }
}

__global__ __launch_bounds__(256)
void kpatch2(const u16* __restrict__ qx, const u16* __restrict__ kv,
             const float* __restrict__ factor,
             const float* __restrict__ w3, const float* __restrict__ b3,
             const float* __restrict__ w5, const float* __restrict__ b5,
             const float* __restrict__ w7, const float* __restrict__ b7,
             u16* __restrict__ xout) {
  const int bid = blockIdx.x;           // b*512 + h*64 + tile
  const int b = bid >> 9;
  const int h = (bid >> 6) & 7;
  const int tile = bid & 63;
  const int y0 = (tile >> 3) * 16, x0 = (tile & 7) * 16;
  const int tid = threadIdx.x;

  __shared__ u16 vt[22][22][32];
  __shared__ u16 qt[256][32];
  __shared__ float fsm[32][32];

  const size_t tokbase = (size_t)b * TPB;
  for (int idx = tid; idx < 22 * 22 * 4; idx += 256) {
    int pos = idx >> 2, c8 = (idx & 3) * 8;
    int py = pos / 22, px = pos - py * 22;
    int y = y0 + py - 3, x = x0 + px - 3;
    uint4 v = make_uint4(0u, 0u, 0u, 0u);
    if (y >= 0 && y < HH && x >= 0 && x < WW)
      v = *(const uint4*)(kv + (tokbase + (y << 7) + x) * 512 + 256 + h * CHD + c8);
    *(uint4*)&vt[py][px][c8] = v;
  }
  for (int idx = tid; idx < 256 * 4; idx += 256) {
    int pos = idx >> 2, c8 = (idx & 3) * 8;
    int y = y0 + (pos >> 4), x = x0 + (pos & 15);
    *(uint4*)&qt[pos][c8] =
        *(const uint4*)(qx + (tokbase + (y << 7) + x) * CDIM + h * CHD + c8);
  }
  for (int idx = tid; idx < 1024; idx += 256)
    fsm[idx >> 5][idx & 31] = factor[(size_t)((b * 8 + h) << 10) + idx];
  __syncthreads();

  const int c = tid & 31;
  const int pg = tid >> 5;
  float freg[32];
#pragma unroll
  for (int cc = 0; cc < 32; ++cc) freg[cc] = fsm[cc][c];

  const size_t obase = (tokbase + (y0 << 7) + x0) * CDIM + h * CHD + c;
  if (h < 2)
    conv_tail<3>(w3 + (h * 32 + c) * 9, b3[h * 32 + c], vt, qt, freg, c, pg, obase, xout);
  else if (h < 5)
    conv_tail<5>(w5 + ((h - 2) * 32 + c) * 25, b5[(h - 2) * 32 + c], vt, qt, freg, c, pg, obase, xout);
  else
    conv_tail<7>(w7 + ((h - 5) * 32 + c) * 49, b7[(h - 5) * 32 + c], vt, qt, freg, c, pg, obase, xout);
}

// ---------------- det branch ------------------------------------------------
__global__ __launch_bounds__(128)
void kdet(const u16* __restrict__ qx, const u16* __restrict__ kv,
          u16* __restrict__ xout) {
  const int bid = blockIdx.x;   // b*8+h
  const int b = bid >> 3, h = bid & 7;
  const int tid = threadIdx.x;
  __shared__ float qd[100][32], kd[100][32], vd[100][32];
  __shared__ float pd[100][101];
  const size_t rq = ((size_t)b * TPB + NTOK) * CDIM;
  const size_t rk = ((size_t)b * TPB + NTOK) * 512;
  for (int flat = tid; flat < 100 * 32; flat += 128) {
    int t = flat >> 5, cc = flat & 31;
    qd[t][cc] = bf2f(qx[rq + (size_t)t * CDIM + h * CHD + cc]);
    kd[t][cc] = bf2f(kv[rk + (size_t)t * 512 + h * CHD + cc]);
    vd[t][cc] = bf2f(kv[rk + (size_t)t * 512 + 256 + h * CHD + cc]);
  }
  __syncthreads();
  const int r = tid;
  if (r < 100) {
    float mx = -1e30f;
    for (int j = 0; j < 100; ++j) {
      float s = 0.f;
#pragma unroll
      for (int cc = 0; cc < 32; ++cc) s += qd[r][cc] * kd[j][cc];
      s *= SCALE;
      pd[r][j] = s;
      mx = fmaxf(mx, s);
    }
    float sum = 0.f;
    for (int j = 0; j < 100; ++j) {
      float e = __expf(pd[r][j] - mx);
      pd[r][j] = e;
      sum += e;
    }
    float inv = 1.f / sum;
    for (int d = 0; d < 32; ++d) {
      float o = 0.f;
      for (int j = 0; j < 100; ++j) o += pd[r][j] * vd[j][d];
      xout[rq + (size_t)r * CDIM + h * CHD + d] = f2bf(o * inv);
    }
  }
}

// ---------------- launch ----------------------------------------------------
extern "C" void kernel_launch(void* const* d_in, const int* in_sizes, int n_in,
                              void* d_out, int out_size, void* d_ws, size_t ws_size,
                              hipStream_t stream) {
  if (ws_size < B_END) return;   // clean diagnostic instead of OOB crash

  const float* x      = (const float*)d_in[0];
  const float* det    = (const float*)d_in[1];
  const float* qkv_w  = (const float*)d_in[4];
  const float* qkv_b  = (const float*)d_in[5];
  const float* proj_w = (const float*)d_in[6];
  const float* proj_b = (const float*)d_in[7];
  const float* w3     = (const float*)d_in[8];
  const float* b3     = (const float*)d_in[9];
  const float* w5     = (const float*)d_in[10];
  const float* b5     = (const float*)d_in[11];
  const float* w7     = (const float*)d_in[12];
  const float* b7     = (const float*)d_in[13];

  char* wsb = (char*)d_ws;
  u16* qx      = (u16*)(wsb + B_QX);
  u16* kv      = (u16*)(wsb + B_KVB);
  u16* WqT     = (u16*)(wsb + B_WQT);
  u16* WpT     = (u16*)(wsb + B_WPT);
  float* pm    = (float*)(wsb + B_PM);
  float* ps    = (float*)(wsb + B_PS);
  float* fpart = (float*)(wsb + B_FPART);
  float* factor= (float*)(wsb + B_FACTOR);
  float* lse   = (float*)(wsb + B_LSE);
  float* out   = (float*)d_out;

  wconv<<<1024, 256, 0, stream>>>(qkv_w, proj_w, WqT, WpT);

  dim3 g1((ROWS + 127) / 128, C3 / 128);
  gemm_qkv<<<g1, 256, 0, stream>>>(x, det, WqT, qkv_b, qx, kv);

  kstats<<<BATCH * 8 * SCH, 256, 0, stream>>>(kv, pm, ps);
  kmerge<<<4, 256, 0, stream>>>(pm, ps, lse);
  kfactor<<<BATCH * 8 * FCH, 256, 0, stream>>>(kv, lse, fpart);
  fmerge<<<128, 256, 0, stream>>>(fpart, factor);

  kpatch2<<<BATCH * 8 * 64, 256, 0, stream>>>(qx, kv, factor,
                                              w3, b3, w5, b5, w7, b7, qx);
  kdet<<<BATCH * 8, 128, 0, stream>>>(qx, kv, qx);

  dim3 g2((ROWS + 127) / 128, CDIM / 128);
  gemm_proj<<<g2, 256, 0, stream>>>(qx, WpT, proj_b, out);
}

// Round 4
// 442.730 us; speedup vs baseline: 4.2160x; 1.1653x over previous
//
#include <hip/hip_runtime.h>
#include <hip/hip_fp16.h>

// ---------------- problem constants ----------------
#define NHEADS 8
#define CHD 32
#define CDIM 256
#define C3 768
#define NTOK 16384
#define MDET 100
#define TPB (NTOK + MDET)      // 16484
#define BATCH 4
#define ROWS (BATCH * TPB)     // 65936
#define HH 128
#define WW 128
#define SCALE 0.17677669529663687f
#define SCH 32
#define FCH 16

typedef unsigned short u16;
typedef __attribute__((ext_vector_type(8))) __bf16 bf16x8;
typedef __attribute__((ext_vector_type(4))) float f32x4;

__device__ __forceinline__ float bf2f(u16 u) {
  union { unsigned int i; float f; } z; z.i = ((unsigned int)u) << 16; return z.f;
}
__device__ __forceinline__ u16 f2bf(float f) {
  __bf16 h = (__bf16)f;
  return __builtin_bit_cast(unsigned short, h);
}

// ---- ws layout (byte offsets); total 104,296,448 B (fits: proven round 3) ----
static const size_t B_QX     = 0;                                  // u16 [ROWS][256] q, later xout
static const size_t B_KPL    = B_QX + (size_t)ROWS * 256 * 2;      // u16 [4][8][TPB][32] k planar
static const size_t B_VPL    = B_KPL + (size_t)ROWS * 256 * 2;     // f16 [4][8][TPB][32] v planar
static const size_t B_WQT    = B_VPL + (size_t)ROWS * 256 * 2;     // u16 [768][256]
static const size_t B_WPT    = B_WQT + (size_t)768 * 256 * 2;      // u16 [256][256]
static const size_t B_PM     = B_WPT + (size_t)256 * 256 * 2;      // f32 [1024][32]
static const size_t B_PS     = B_PM + 1024 * 32 * 4;
static const size_t B_FPART  = B_PS + 1024 * 32 * 4;               // f32 [512][1024]
static const size_t B_FACTOR = B_FPART + (size_t)512 * 1024 * 4;   // f32 [32][1024]
static const size_t B_LSE    = B_FACTOR + 32768 * 4;               // f32 [1024]
static const size_t B_END    = B_LSE + 1024 * 4;

// ---------------- weight convert+transpose: W[k][n] -> Wt bf16 [n][k] -------
__global__ __launch_bounds__(256)
void wconv(const float* __restrict__ qkv_w, const float* __restrict__ proj_w,
           u16* __restrict__ WqT, u16* __restrict__ WpT) {
  int o = blockIdx.x * 256 + threadIdx.x;
  if (o < 768 * 256) {
    int n = o >> 8, k = o & 255;
    WqT[o] = f2bf(qkv_w[(size_t)k * C3 + n]);
  } else {
    int p = o - 768 * 256;
    int n = p >> 8, k = p & 255;
    WpT[p] = f2bf(proj_w[(size_t)k * CDIM + n]);
  }
}

// ---------------- MFMA GEMM: (x|det) @ qkv_w -> q rows + planar k/v ---------
__global__ __launch_bounds__(256)
void gemm_qkv(const float* __restrict__ x, const float* __restrict__ det,
              const u16* __restrict__ WqT, const float* __restrict__ bias,
              u16* __restrict__ qx, u16* __restrict__ kpl, __half* __restrict__ vpl) {
  const int row0 = blockIdx.x * 128;
  const int col0 = blockIdx.y * 128;
  const int tid = threadIdx.x;
  const int lane = tid & 63;
  const int wid = tid >> 6;
  const int wm = (wid & 1) * 64;
  const int wn = (wid >> 1) * 64;
  const int m16 = lane & 15;
  const int kg8 = (lane >> 4) * 8;

  __shared__ u16 As[128][72];
  __shared__ u16 Bs[128][72];

  const int sr = tid >> 1;
  const int sk = (tid & 1) * 32;

  int grow = row0 + sr;
  int crow = grow < ROWS ? grow : ROWS - 1;
  int bb = crow / TPB, tt = crow - bb * TPB;
  const float* aptr = (tt < NTOK)
      ? x + (size_t)(bb * NTOK + tt) * CDIM
      : det + (size_t)(bb * MDET + (tt - NTOK)) * CDIM;
  const u16* bptr = WqT + (size_t)(col0 + sr) * CDIM;

  f32x4 acc[4][4];
#pragma unroll
  for (int ni = 0; ni < 4; ++ni) {
    float bv = bias[col0 + wn + ni * 16 + m16];
#pragma unroll
    for (int mi = 0; mi < 4; ++mi)
      acc[mi][ni] = (f32x4){bv, bv, bv, bv};
  }

  for (int k0 = 0; k0 < CDIM; k0 += 64) {
#pragma unroll
    for (int j = 0; j < 4; ++j) {
      float4 v0 = *(const float4*)(aptr + k0 + sk + j * 8);
      float4 v1 = *(const float4*)(aptr + k0 + sk + j * 8 + 4);
      ushort4 u0, u1;
      u0.x = f2bf(v0.x); u0.y = f2bf(v0.y); u0.z = f2bf(v0.z); u0.w = f2bf(v0.w);
      u1.x = f2bf(v1.x); u1.y = f2bf(v1.y); u1.z = f2bf(v1.z); u1.w = f2bf(v1.w);
      *(ushort4*)&As[sr][sk + j * 8] = u0;
      *(ushort4*)&As[sr][sk + j * 8 + 4] = u1;
      *(uint4*)&Bs[sr][sk + j * 8] = *(const uint4*)(bptr + k0 + sk + j * 8);
    }
    __syncthreads();
#pragma unroll
    for (int kk = 0; kk < 2; ++kk) {
      bf16x8 af[4], bfr[4];
#pragma unroll
      for (int mi = 0; mi < 4; ++mi)
        af[mi] = *(const bf16x8*)&As[wm + mi * 16 + m16][kk * 32 + kg8];
#pragma unroll
      for (int ni = 0; ni < 4; ++ni)
        bfr[ni] = *(const bf16x8*)&Bs[wn + ni * 16 + m16][kk * 32 + kg8];
#pragma unroll
      for (int mi = 0; mi < 4; ++mi)
#pragma unroll
        for (int ni = 0; ni < 4; ++ni)
          acc[mi][ni] = __builtin_amdgcn_mfma_f32_16x16x32_bf16(
              af[mi], bfr[ni], acc[mi][ni], 0, 0, 0);
    }
    __syncthreads();
  }

  const int rbase = (lane >> 4) * 4;
#pragma unroll
  for (int mi = 0; mi < 4; ++mi) {
#pragma unroll
    for (int r = 0; r < 4; ++r) {
      int rr = row0 + wm + mi * 16 + rbase + r;
      if (rr >= ROWS) continue;
      int b = rr / TPB, t = rr - b * TPB;
#pragma unroll
      for (int ni = 0; ni < 4; ++ni) {
        int col = col0 + wn + ni * 16 + m16;
        float v = acc[mi][ni][r];
        if (col < 256) {
          qx[(size_t)rr * 256 + col] = f2bf(v);
        } else if (col < 512) {
          int cc = col - 256;
          kpl[((size_t)(b * 8 + (cc >> 5)) * TPB + t) * 32 + (cc & 31)] = f2bf(v);
        } else {
          int cc = col - 512;
          vpl[((size_t)(b * 8 + (cc >> 5)) * TPB + t) * 32 + (cc & 31)] = __float2half(v);
        }
      }
    }
  }
}

// ---------------- MFMA GEMM: xout(bf16) @ proj_w -> d_out fp32 (split) ------
__global__ __launch_bounds__(256)
void gemm_proj(const u16* __restrict__ xin, const u16* __restrict__ WpT,
               const float* __restrict__ bias, float* __restrict__ dout) {
  const int row0 = blockIdx.x * 128;
  const int col0 = blockIdx.y * 128;
  const int tid = threadIdx.x;
  const int lane = tid & 63;
  const int wid = tid >> 6;
  const int wm = (wid & 1) * 64;
  const int wn = (wid >> 1) * 64;
  const int m16 = lane & 15;
  const int kg8 = (lane >> 4) * 8;

  __shared__ u16 As[128][72];
  __shared__ u16 Bs[128][72];

  const int sr = tid >> 1;
  const int sk = (tid & 1) * 32;

  int grow = row0 + sr;
  int crow = grow < ROWS ? grow : ROWS - 1;
  const u16* aptr = xin + (size_t)crow * CDIM;
  const u16* bptr = WpT + (size_t)(col0 + sr) * CDIM;

  f32x4 acc[4][4];
#pragma unroll
  for (int ni = 0; ni < 4; ++ni) {
    float bv = bias[col0 + wn + ni * 16 + m16];
#pragma unroll
    for (int mi = 0; mi < 4; ++mi)
      acc[mi][ni] = (f32x4){bv, bv, bv, bv};
  }

  for (int k0 = 0; k0 < CDIM; k0 += 64) {
#pragma unroll
    for (int j = 0; j < 4; ++j) {
      *(uint4*)&As[sr][sk + j * 8] = *(const uint4*)(aptr + k0 + sk + j * 8);
      *(uint4*)&Bs[sr][sk + j * 8] = *(const uint4*)(bptr + k0 + sk + j * 8);
    }
    __syncthreads();
#pragma unroll
    for (int kk = 0; kk < 2; ++kk) {
      bf16x8 af[4], bfr[4];
#pragma unroll
      for (int mi = 0; mi < 4; ++mi)
        af[mi] = *(const bf16x8*)&As[wm + mi * 16 + m16][kk * 32 + kg8];
#pragma unroll
      for (int ni = 0; ni < 4; ++ni)
        bfr[ni] = *(const bf16x8*)&Bs[wn + ni * 16 + m16][kk * 32 + kg8];
#pragma unroll
      for (int mi = 0; mi < 4; ++mi)
#pragma unroll
        for (int ni = 0; ni < 4; ++ni)
          acc[mi][ni] = __builtin_amdgcn_mfma_f32_16x16x32_bf16(
              af[mi], bfr[ni], acc[mi][ni], 0, 0, 0);
    }
    __syncthreads();
  }

  const int rbase = (lane >> 4) * 4;
#pragma unroll
  for (int mi = 0; mi < 4; ++mi) {
#pragma unroll
    for (int r = 0; r < 4; ++r) {
      int rr = row0 + wm + mi * 16 + rbase + r;
      if (rr >= ROWS) continue;
      int b = rr / TPB, t = rr - b * TPB;
      float* dst = (t < NTOK)
          ? dout + ((size_t)b * NTOK + t) * CDIM
          : dout + (size_t)BATCH * NTOK * CDIM + ((size_t)b * MDET + (t - NTOK)) * CDIM;
#pragma unroll
      for (int ni = 0; ni < 4; ++ni)
        dst[col0 + wn + ni * 16 + m16] = acc[mi][ni][r];
    }
  }
}

// ---------------- softmax stats over tokens, per (b,h,c) --------------------
__global__ __launch_bounds__(256)
void kstats(const u16* __restrict__ kpl, float* __restrict__ pm,
            float* __restrict__ ps) {
  const int bid = blockIdx.x;
  const int chunk = bid & (SCH - 1);
  const int h = (bid / SCH) & 7;
  const int b = bid / (SCH * 8);
  const int tid = threadIdx.x;
  const int c = tid & 31, sub = tid >> 5;
  const size_t base = ((size_t)(b * 8 + h) * TPB) * 32 + c;
  const int t0 = chunk * (NTOK / SCH);
  float m = -1e30f, s = 0.f;
  for (int i = sub; i < NTOK / SCH; i += 8) {
    float k = bf2f(kpl[base + (size_t)(t0 + i) * 32]);
    float nm = fmaxf(m, k);
    s = s * __expf(m - nm) + __expf(k - nm);
    m = nm;
  }
  __shared__ float sm[8][32], ss[8][32];
  sm[sub][c] = m; ss[sub][c] = s;
  __syncthreads();
  if (sub == 0) {
    for (int j = 1; j < 8; ++j) {
      float m2 = sm[j][c], s2 = ss[j][c];
      float nm = fmaxf(m, m2);
      s = s * __expf(m - nm) + s2 * __expf(m2 - nm);
      m = nm;
    }
    pm[bid * 32 + c] = m;
    ps[bid * 32 + c] = s;
  }
}

__global__ void kmerge(const float* __restrict__ pm, const float* __restrict__ ps,
                       float* __restrict__ lse) {
  int g = blockIdx.x * blockDim.x + threadIdx.x;
  if (g >= BATCH * 8 * 32) return;
  int c = g & 31, bh = g >> 5;
  float m = -1e30f, s = 0.f;
  for (int ch = 0; ch < SCH; ++ch) {
    int bid = bh * SCH + ch;
    float m2 = pm[bid * 32 + c], s2 = ps[bid * 32 + c];
    float nm = fmaxf(m, m2);
    s = s * __expf(m - nm) + s2 * __expf(m2 - nm);
    m = nm;
  }
  lse[g] = m + logf(s);
}

// ---------------- factor = ksoftmax^T @ V (split-K over tokens) -------------
__global__ __launch_bounds__(256)
void kfactor(const u16* __restrict__ kpl, const __half* __restrict__ vpl,
             const float* __restrict__ lse, float* __restrict__ fpart) {
  const int bid = blockIdx.x;               // (b*8+h)*FCH + chunk
  const int chunk = bid & (FCH - 1);
  const int h = (bid / FCH) & 7;
  const int b = bid / (FCH * 8);
  const int tid = threadIdx.x;
  const int c = tid & 31;
  const int d0 = (tid >> 5) * 4;
  const float lse_c = lse[(b * 8 + h) * 32 + c];
  __shared__ float wsm[64][32];
  __shared__ float vsm[64][33];
  float a0 = 0.f, a1 = 0.f, a2 = 0.f, a3 = 0.f;
  const int t0 = chunk * (NTOK / FCH);
  for (int st = 0; st < (NTOK / FCH) / 64; ++st) {
    int tb = t0 + st * 64;
    const size_t base = ((size_t)(b * 8 + h) * TPB + tb) * 32;
#pragma unroll
    for (int i = 0; i < 8; ++i) {
      int flat = tid + i * 256;
      int tt = flat >> 5;
      int cc = flat & 31;
      wsm[tt][cc] = __expf(bf2f(kpl[base + flat]) - lse_c);
      vsm[tt][cc] = __half2float(vpl[base + flat]);
    }
    __syncthreads();
#pragma unroll 4
    for (int tt = 0; tt < 64; ++tt) {
      float w = wsm[tt][c];
      a0 += w * vsm[tt][d0 + 0];
      a1 += w * vsm[tt][d0 + 1];
      a2 += w * vsm[tt][d0 + 2];
      a3 += w * vsm[tt][d0 + 3];
    }
    __syncthreads();
  }
  float* fp = fpart + ((size_t)bid * 32 + c) * 32 + d0;
  fp[0] = a0; fp[1] = a1; fp[2] = a2; fp[3] = a3;
}

__global__ void fmerge(const float* __restrict__ fpart, float* __restrict__ factor) {
  int o = blockIdx.x * 256 + threadIdx.x;
  if (o >= BATCH * 8 * CHD * CHD) return;
  int cd = o & 1023, bh = o >> 10;
  float s = 0.f;
  for (int ch = 0; ch < FCH; ++ch)
    s += fpart[((size_t)(bh * FCH + ch) << 10) + cd];
  factor[o] = s;
}

// ---------------- patch: MFMA fa + register-row conv + assemble -------------
// block = (b, h, 16x16 tile). vt: [c][y][x] f16, row padded to 24, +8 skew/c.
template <int K>
__global__ __launch_bounds__(256)
void kpatch3(const u16* __restrict__ qx, const __half* __restrict__ vpl,
             const float* __restrict__ factor,
             const float* __restrict__ wk, const float* __restrict__ bk,
             int h_base, int nh, u16* __restrict__ xout) {
  constexpr int HE = 16 + K - 1;       // halo extent
  constexpr int PADK = K / 2;
  constexpr int CSTRIDE = HE * 24 + 8; // u16 per channel (16B-aligned, skewed)

  __shared__ u16 vt[32 * CSTRIDE];
  __shared__ u16 fa_s[256 * 32];
  __shared__ u16 FT[32 * 32];

  const int bid = blockIdx.x;
  const int tile = bid & 63;
  const int rem = bid >> 6;
  const int h = h_base + (rem % nh);
  const int b = rem / nh;
  const int y0 = (tile >> 3) * 16, x0 = (tile & 7) * 16;
  const int tid = threadIdx.x;
  const int btok = b * TPB;
  const size_t vbase = (size_t)(b * 8 + h) * TPB * 32;

  // ---- stage vt (planar v, f16 raw copy, transposed to [c][y][x]) ----
  for (int flat = tid; flat < HE * HE * 8; flat += 256) {
    int pos = flat >> 3, c4 = (flat & 7) * 4;
    int y = pos / HE, xx_ = pos - y * HE;
    int yy = y0 + y - PADK, xx = x0 + xx_ - PADK;
    ushort4 v = make_ushort4(0, 0, 0, 0);
    if (yy >= 0 && yy < HH && xx >= 0 && xx < WW)
      v = *(const ushort4*)((const u16*)vpl + vbase + (size_t)(yy * WW + xx) * 32 + c4);
    vt[(c4 + 0) * CSTRIDE + y * 24 + xx_] = v.x;
    vt[(c4 + 1) * CSTRIDE + y * 24 + xx_] = v.y;
    vt[(c4 + 2) * CSTRIDE + y * 24 + xx_] = v.z;
    vt[(c4 + 3) * CSTRIDE + y * 24 + xx_] = v.w;
  }
  // ---- stage FT[d][cc] = factor[cc][d] as bf16 ----
  {
    int flat = tid;
    int d = flat >> 5, cc = flat & 31;
    FT[d * 32 + cc] = f2bf(factor[(size_t)((b * 8 + h) << 10) + cc * 32 + d]);
    flat = tid + 256; d = flat >> 5; cc = flat & 31;
    FT[d * 32 + cc] = f2bf(factor[(size_t)((b * 8 + h) << 10) + cc * 32 + d]);
    flat = tid + 512; d = flat >> 5; cc = flat & 31;
    FT[d * 32 + cc] = f2bf(factor[(size_t)((b * 8 + h) << 10) + cc * 32 + d]);
    flat = tid + 768; d = flat >> 5; cc = flat & 31;
    FT[d * 32 + cc] = f2bf(factor[(size_t)((b * 8 + h) << 10) + cc * 32 + d]);
  }
  __syncthreads();

  // ---- phase 1: fa = q @ F via MFMA (A from global q, B = FT in LDS) ----
  {
    const int lane = tid & 63;
    const int wid = tid >> 6;
    const int m16 = lane & 15;
    const int kg8 = (lane >> 4) * 8;
    bf16x8 bfr[2];
#pragma unroll
    for (int ni = 0; ni < 2; ++ni)
      bfr[ni] = *(const bf16x8*)&FT[(ni * 16 + m16) * 32 + kg8];
    f32x4 acc[4][2];
#pragma unroll
    for (int mi = 0; mi < 4; ++mi)
#pragma unroll
      for (int ni = 0; ni < 2; ++ni)
        acc[mi][ni] = (f32x4){0.f, 0.f, 0.f, 0.f};
#pragma unroll
    for (int mi = 0; mi < 4; ++mi) {
      int pos = wid * 64 + mi * 16 + m16;
      int token = (y0 + (pos >> 4)) * 128 + x0 + (pos & 15);
      bf16x8 af = *(const bf16x8*)(qx + (size_t)(btok + token) * 256 + h * 32 + kg8);
#pragma unroll
      for (int ni = 0; ni < 2; ++ni)
        acc[mi][ni] = __builtin_amdgcn_mfma_f32_16x16x32_bf16(
            af, bfr[ni], acc[mi][ni], 0, 0, 0);
    }
#pragma unroll
    for (int mi = 0; mi < 4; ++mi)
#pragma unroll
      for (int ni = 0; ni < 2; ++ni)
#pragma unroll
        for (int r = 0; r < 4; ++r) {
          int pos = wid * 64 + mi * 16 + (lane >> 4) * 4 + r;
          fa_s[pos * 32 + ni * 16 + m16] = f2bf(acc[mi][ni][r]);
        }
  }
  __syncthreads();

  // ---- phase 2: depthwise conv from register rows + combine ----
  const int c = tid & 31;
  const int syg = tid >> 5;           // 0..7
  const int widx = (h - h_base) * 32 + c;
  float wreg[K * K];
#pragma unroll
  for (int i = 0; i < K * K; ++i) wreg[i] = wk[widx * K * K + i];
  const float wb = bk[widx];

  float o[2][16];
#pragma unroll
  for (int ri = 0; ri < 2; ++ri)
#pragma unroll
    for (int p = 0; p < 16; ++p) o[ri][p] = 0.f;

#pragma unroll
  for (int ri = 0; ri < 2; ++ri) {
    const int yy = syg + ri * 8;
#pragma unroll
    for (int dy = 0; dy < K; ++dy) {
      const int vrow = yy + dy;
      union { uint4 q[3]; __half hh[24]; } row;
      row.q[0] = *(const uint4*)&vt[c * CSTRIDE + vrow * 24 + 0];
      row.q[1] = *(const uint4*)&vt[c * CSTRIDE + vrow * 24 + 8];
      row.q[2] = *(const uint4*)&vt[c * CSTRIDE + vrow * 24 + 16];
      float frow[HE];
#pragma unroll
      for (int j = 0; j < HE; ++j) frow[j] = __half2float(row.hh[j]);
#pragma unroll
      for (int dx = 0; dx < K; ++dx) {
        const float wv = wreg[dy * K + dx];
#pragma unroll
        for (int p = 0; p < 16; ++p)
          o[ri][p] += wv * frow[p + dx];
      }
    }
  }

  // combine: res = SCALE*fa + q*(conv + bias)
#pragma unroll
  for (int ri = 0; ri < 2; ++ri) {
    const int yy = syg + ri * 8;
#pragma unroll
    for (int p = 0; p < 16; ++p) {
      const int pos = yy * 16 + p;
      const int token = (y0 + yy) * 128 + x0 + p;
      const size_t gidx = (size_t)(btok + token) * 256 + h * 32 + c;
      float fa = bf2f(fa_s[pos * 32 + c]);
      float qv = bf2f(qx[gidx]);
      xout[gidx] = f2bf(SCALE * fa + qv * (o[ri][p] + wb));
    }
  }
}

// ---------------- det branch ------------------------------------------------
__global__ __launch_bounds__(128)
void kdet(const u16* __restrict__ qx, const u16* __restrict__ kpl,
          const __half* __restrict__ vpl, u16* __restrict__ xout) {
  const int bid = blockIdx.x;   // b*8+h
  const int b = bid >> 3, h = bid & 7;
  const int tid = threadIdx.x;
  __shared__ float qd[100][32], kd[100][32], vd[100][32];
  __shared__ float pd[100][101];
  const size_t rq = ((size_t)b * TPB + NTOK) * CDIM;
  const size_t rp = ((size_t)(b * 8 + h) * TPB + NTOK) * 32;
  for (int flat = tid; flat < 100 * 32; flat += 128) {
    int t = flat >> 5, cc = flat & 31;
    qd[t][cc] = bf2f(qx[rq + (size_t)t * CDIM + h * CHD + cc]);
    kd[t][cc] = bf2f(kpl[rp + (size_t)t * 32 + cc]);
    vd[t][cc] = __half2float(vpl[rp + (size_t)t * 32 + cc]);
  }
  __syncthreads();
  const int r = tid;
  if (r < 100) {
    float mx = -1e30f;
    for (int j = 0; j < 100; ++j) {
      float s = 0.f;
#pragma unroll
      for (int cc = 0; cc < 32; ++cc) s += qd[r][cc] * kd[j][cc];
      s *= SCALE;
      pd[r][j] = s;
      mx = fmaxf(mx, s);
    }
    float sum = 0.f;
    for (int j = 0; j < 100; ++j) {
      float e = __expf(pd[r][j] - mx);
      pd[r][j] = e;
      sum += e;
    }
    float inv = 1.f / sum;
    for (int d = 0; d < 32; ++d) {
      float o = 0.f;
      for (int j = 0; j < 100; ++j) o += pd[r][j] * vd[j][d];
      xout[rq + (size_t)r * CDIM + h * CHD + d] = f2bf(o * inv);
    }
  }
}

// ---------------- launch ----------------------------------------------------
extern "C" void kernel_launch(void* const* d_in, const int* in_sizes, int n_in,
                              void* d_out, int out_size, void* d_ws, size_t ws_size,
                              hipStream_t stream) {
  if (ws_size < B_END) return;   // clean diagnostic instead of OOB crash

  const float* x      = (const float*)d_in[0];
  const float* det    = (const float*)d_in[1];
  const float* qkv_w  = (const float*)d_in[4];
  const float* qkv_b  = (const float*)d_in[5];
  const float* proj_w = (const float*)d_in[6];
  const float* proj_b = (const float*)d_in[7];
  const float* w3     = (const float*)d_in[8];
  const float* b3     = (const float*)d_in[9];
  const float* w5     = (const float*)d_in[10];
  const float* b5     = (const float*)d_in[11];
  const float* w7     = (const float*)d_in[12];
  const float* b7     = (const float*)d_in[13];

  char* wsb = (char*)d_ws;
  u16* qx      = (u16*)(wsb + B_QX);
  u16* kpl     = (u16*)(wsb + B_KPL);
  __half* vpl  = (__half*)(wsb + B_VPL);
  u16* WqT     = (u16*)(wsb + B_WQT);
  u16* WpT     = (u16*)(wsb + B_WPT);
  float* pm    = (float*)(wsb + B_PM);
  float* ps    = (float*)(wsb + B_PS);
  float* fpart = (float*)(wsb + B_FPART);
  float* factor= (float*)(wsb + B_FACTOR);
  float* lse   = (float*)(wsb + B_LSE);
  float* out   = (float*)d_out;

  wconv<<<1024, 256, 0, stream>>>(qkv_w, proj_w, WqT, WpT);

  dim3 g1((ROWS + 127) / 128, C3 / 128);
  gemm_qkv<<<g1, 256, 0, stream>>>(x, det, WqT, qkv_b, qx, kpl, vpl);

  kstats<<<BATCH * 8 * SCH, 256, 0, stream>>>(kpl, pm, ps);
  kmerge<<<4, 256, 0, stream>>>(pm, ps, lse);
  kfactor<<<BATCH * 8 * FCH, 256, 0, stream>>>(kpl, vpl, lse, fpart);
  fmerge<<<128, 256, 0, stream>>>(fpart, factor);

  kpatch3<3><<<BATCH * 2 * 64, 256, 0, stream>>>(qx, vpl, factor, w3, b3, 0, 2, qx);
  kpatch3<5><<<BATCH * 3 * 64, 256, 0, stream>>>(qx, vpl, factor, w5, b5, 2, 3, qx);
  kpatch3<7><<<BATCH * 3 * 64, 256, 0, stream>>>(qx, vpl, factor, w7, b7, 5, 3, qx);

  kdet<<<BATCH * 8, 128, 0, stream>>>(qx, kpl, vpl, qx);

  dim3 g2((ROWS + 127) / 128, CDIM / 128);
  gemm_proj<<<g2, 256, 0, stream>>>(qx, WpT, proj_b, out);
}

// Round 7
// 425.445 us; speedup vs baseline: 4.3873x; 1.0406x over previous
//
#include <hip/hip_runtime.h>
#include <hip/hip_fp16.h>

// ---------------- problem constants ----------------
#define NHEADS 8
#define CHD 32
#define CDIM 256
#define C3 768
#define NTOK 16384
#define MDET 100
#define TPB (NTOK + MDET)      // 16484
#define BATCH 4
#define ROWS (BATCH * TPB)     // 65936
#define HH 128
#define WW 128
#define SCALE 0.17677669529663687f
#define SCH 32
#define FCH 16

typedef unsigned short u16;
typedef __attribute__((ext_vector_type(8))) __bf16 bf16x8;
typedef __attribute__((ext_vector_type(4))) float f32x4;

__device__ __forceinline__ float bf2f(u16 u) {
  union { unsigned int i; float f; } z; z.i = ((unsigned int)u) << 16; return z.f;
}
__device__ __forceinline__ u16 f2bf(float f) {
  __bf16 h = (__bf16)f;
  return __builtin_bit_cast(unsigned short, h);
}

// ---- ws layout (byte offsets); total 104,296,448 B (proven fits) ----
static const size_t B_QX     = 0;                                  // u16 [ROWS][256] q, later xout
static const size_t B_KPL    = B_QX + (size_t)ROWS * 256 * 2;      // u16 [4][8][TPB][32] k planar
static const size_t B_VPL    = B_KPL + (size_t)ROWS * 256 * 2;     // f16 [4][8][TPB][32] v planar
static const size_t B_WQT    = B_VPL + (size_t)ROWS * 256 * 2;     // u16 [768][256]
static const size_t B_WPT    = B_WQT + (size_t)768 * 256 * 2;      // u16 [256][256]
static const size_t B_PM     = B_WPT + (size_t)256 * 256 * 2;      // f32 [1024][32]
static const size_t B_PS     = B_PM + 1024 * 32 * 4;
static const size_t B_FPART  = B_PS + 1024 * 32 * 4;               // f32 [512][1024]
static const size_t B_FACTOR = B_FPART + (size_t)512 * 1024 * 4;   // f32 [32][1024]
static const size_t B_LSE    = B_FACTOR + 32768 * 4;               // f32 [1024]
static const size_t B_END    = B_LSE + 1024 * 4;

// xbf (bf16 gathered A, 33.8 MB) lives in d_out-as-scratch; overwritten by
// gemm_proj at the end (gemm_proj reads only qx/WpT, so no race).

#define XCHUNKS (ROWS * 32)            // 8-elem chunks of xbf (256/8 = 32 per row)
#define WQCH (768 * 256 / 8)
#define WPCH (256 * 256 / 8)

// ---------------- prep: gather x|det -> bf16, transpose weights -> bf16 -----
__global__ __launch_bounds__(256)
void prep(const float* __restrict__ x, const float* __restrict__ det,
          const float* __restrict__ qkv_w, const float* __restrict__ proj_w,
          u16* __restrict__ xbf, u16* __restrict__ WqT, u16* __restrict__ WpT) {
  const int total = XCHUNKS + WQCH + WPCH;
  for (int idx = blockIdx.x * 256 + threadIdx.x; idx < total; idx += gridDim.x * 256) {
    if (idx < XCHUNKS) {
      int r = idx >> 5;
      int co = (idx & 31) * 8;
      int b = r / TPB, t = r - b * TPB;
      const float* src = (t < NTOK)
          ? x + (size_t)(b * NTOK + t) * CDIM + co
          : det + (size_t)(b * MDET + (t - NTOK)) * CDIM + co;
      float4 v0 = *(const float4*)src;
      float4 v1 = *(const float4*)(src + 4);
      ushort4 a, bb;
      a.x = f2bf(v0.x); a.y = f2bf(v0.y); a.z = f2bf(v0.z); a.w = f2bf(v0.w);
      bb.x = f2bf(v1.x); bb.y = f2bf(v1.y); bb.z = f2bf(v1.z); bb.w = f2bf(v1.w);
      *(ushort4*)(xbf + (size_t)idx * 8) = a;
      *(ushort4*)(xbf + (size_t)idx * 8 + 4) = bb;
    } else if (idx < XCHUNKS + WQCH) {
      int o = (idx - XCHUNKS) * 8;
#pragma unroll
      for (int j = 0; j < 8; ++j) {
        int oo = o + j;
        int n = oo >> 8, k = oo & 255;
        WqT[oo] = f2bf(qkv_w[(size_t)k * C3 + n]);
      }
    } else {
      int o = (idx - XCHUNKS - WQCH) * 8;
#pragma unroll
      for (int j = 0; j < 8; ++j) {
        int oo = o + j;
        int n = oo >> 8, k = oo & 255;
        WpT[oo] = f2bf(proj_w[(size_t)k * CDIM + n]);
      }
    }
  }
}

// ---------------- MFMA GEMM: xbf @ qkv_w -> q rows + planar k/v -------------
// XCD-swizzled 1-D grid: bid = (rowl*6 + colb)*8 + xcd, rowb = xcd + 8*rowl.
// All 6 col-tiles of a row-stripe run consecutively on ONE XCD -> A L2-hot.
__global__ __launch_bounds__(256)
void gemm_qkv(const u16* __restrict__ xbf, const u16* __restrict__ WqT,
              const float* __restrict__ bias,
              u16* __restrict__ qx, u16* __restrict__ kpl, __half* __restrict__ vpl) {
  const int bid = blockIdx.x;
  const int xcd = bid & 7;
  const int slot = bid >> 3;
  const int colb = slot % 6;
  const int rowl = slot / 6;
  const int row0 = (xcd + 8 * rowl) * 128;
  const int col0 = colb * 128;

  const int tid = threadIdx.x;
  const int lane = tid & 63;
  const int wid = tid >> 6;
  const int wm = (wid & 1) * 64;
  const int wn = (wid >> 1) * 64;
  const int m16 = lane & 15;
  const int kg8 = (lane >> 4) * 8;

  __shared__ u16 As[128][72];
  __shared__ u16 Bs[128][72];

  const int sr = tid >> 1;
  const int sk = (tid & 1) * 32;

  int grow = row0 + sr;
  int crow = grow < ROWS ? grow : ROWS - 1;
  const u16* aptr = xbf + (size_t)crow * CDIM;
  const u16* bptr = WqT + (size_t)(col0 + sr) * CDIM;

  f32x4 acc[4][4];
#pragma unroll
  for (int ni = 0; ni < 4; ++ni) {
    float bv = bias[col0 + wn + ni * 16 + m16];
#pragma unroll
    for (int mi = 0; mi < 4; ++mi)
      acc[mi][ni] = (f32x4){bv, bv, bv, bv};
  }

  for (int k0 = 0; k0 < CDIM; k0 += 64) {
#pragma unroll
    for (int j = 0; j < 4; ++j) {
      *(uint4*)&As[sr][sk + j * 8] = *(const uint4*)(aptr + k0 + sk + j * 8);
      *(uint4*)&Bs[sr][sk + j * 8] = *(const uint4*)(bptr + k0 + sk + j * 8);
    }
    __syncthreads();
#pragma unroll
    for (int kk = 0; kk < 2; ++kk) {
      bf16x8 af[4], bfr[4];
#pragma unroll
      for (int mi = 0; mi < 4; ++mi)
        af[mi] = *(const bf16x8*)&As[wm + mi * 16 + m16][kk * 32 + kg8];
#pragma unroll
      for (int ni = 0; ni < 4; ++ni)
        bfr[ni] = *(const bf16x8*)&Bs[wn + ni * 16 + m16][kk * 32 + kg8];
#pragma unroll
      for (int mi = 0; mi < 4; ++mi)
#pragma unroll
        for (int ni = 0; ni < 4; ++ni)
          acc[mi][ni] = __builtin_amdgcn_mfma_f32_16x16x32_bf16(
              af[mi], bfr[ni], acc[mi][ni], 0, 0, 0);
    }
    __syncthreads();
  }

  const int rbase = (lane >> 4) * 4;
#pragma unroll
  for (int mi = 0; mi < 4; ++mi) {
#pragma unroll
    for (int r = 0; r < 4; ++r) {
      int rr = row0 + wm + mi * 16 + rbase + r;
      if (rr >= ROWS) continue;
      int b = rr / TPB, t = rr - b * TPB;
#pragma unroll
      for (int ni = 0; ni < 4; ++ni) {
        int col = col0 + wn + ni * 16 + m16;
        float v = acc[mi][ni][r];
        if (col < 256) {
          qx[(size_t)rr * 256 + col] = f2bf(v);
        } else if (col < 512) {
          int cc = col - 256;
          kpl[((size_t)(b * 8 + (cc >> 5)) * TPB + t) * 32 + (cc & 31)] = f2bf(v);
        } else {
          int cc = col - 512;
          vpl[((size_t)(b * 8 + (cc >> 5)) * TPB + t) * 32 + (cc & 31)] = __float2half(v);
        }
      }
    }
  }
}

// ---------------- MFMA GEMM: xout(bf16) @ proj_w -> d_out fp32 (split) ------
__global__ __launch_bounds__(256)
void gemm_proj(const u16* __restrict__ xin, const u16* __restrict__ WpT,
               const float* __restrict__ bias, float* __restrict__ dout) {
  const int row0 = blockIdx.x * 128;
  const int col0 = blockIdx.y * 128;
  const int tid = threadIdx.x;
  const int lane = tid & 63;
  const int wid = tid >> 6;
  const int wm = (wid & 1) * 64;
  const int wn = (wid >> 1) * 64;
  const int m16 = lane & 15;
  const int kg8 = (lane >> 4) * 8;

  __shared__ u16 As[128][72];
  __shared__ u16 Bs[128][72];

  const int sr = tid >> 1;
  const int sk = (tid & 1) * 32;

  int grow = row0 + sr;
  int crow = grow < ROWS ? grow : ROWS - 1;
  const u16* aptr = xin + (size_t)crow * CDIM;
  const u16* bptr = WpT + (size_t)(col0 + sr) * CDIM;

  f32x4 acc[4][4];
#pragma unroll
  for (int ni = 0; ni < 4; ++ni) {
    float bv = bias[col0 + wn + ni * 16 + m16];
#pragma unroll
    for (int mi = 0; mi < 4; ++mi)
      acc[mi][ni] = (f32x4){bv, bv, bv, bv};
  }

  for (int k0 = 0; k0 < CDIM; k0 += 64) {
#pragma unroll
    for (int j = 0; j < 4; ++j) {
      *(uint4*)&As[sr][sk + j * 8] = *(const uint4*)(aptr + k0 + sk + j * 8);
      *(uint4*)&Bs[sr][sk + j * 8] = *(const uint4*)(bptr + k0 + sk + j * 8);
    }
    __syncthreads();
#pragma unroll
    for (int kk = 0; kk < 2; ++kk) {
      bf16x8 af[4], bfr[4];
#pragma unroll
      for (int mi = 0; mi < 4; ++mi)
        af[mi] = *(const bf16x8*)&As[wm + mi * 16 + m16][kk * 32 + kg8];
#pragma unroll
      for (int ni = 0; ni < 4; ++ni)
        bfr[ni] = *(const bf16x8*)&Bs[wn + ni * 16 + m16][kk * 32 + kg8];
#pragma unroll
      for (int mi = 0; mi < 4; ++mi)
#pragma unroll
        for (int ni = 0; ni < 4; ++ni)
          acc[mi][ni] = __builtin_amdgcn_mfma_f32_16x16x32_bf16(
              af[mi], bfr[ni], acc[mi][ni], 0, 0, 0);
    }
    __syncthreads();
  }

  const int rbase = (lane >> 4) * 4;
#pragma unroll
  for (int mi = 0; mi < 4; ++mi) {
#pragma unroll
    for (int r = 0; r < 4; ++r) {
      int rr = row0 + wm + mi * 16 + rbase + r;
      if (rr >= ROWS) continue;
      int b = rr / TPB, t = rr - b * TPB;
      float* dst = (t < NTOK)
          ? dout + ((size_t)b * NTOK + t) * CDIM
          : dout + (size_t)BATCH * NTOK * CDIM + ((size_t)b * MDET + (t - NTOK)) * CDIM;
#pragma unroll
      for (int ni = 0; ni < 4; ++ni)
        dst[col0 + wn + ni * 16 + m16] = acc[mi][ni][r];
    }
  }
}

// ---------------- softmax stats over tokens, per (b,h,c) --------------------
__global__ __launch_bounds__(256)
void kstats(const u16* __restrict__ kpl, float* __restrict__ pm,
            float* __restrict__ ps) {
  const int bid = blockIdx.x;
  const int chunk = bid & (SCH - 1);
  const int h = (bid / SCH) & 7;
  const int b = bid / (SCH * 8);
  const int tid = threadIdx.x;
  const int c = tid & 31, sub = tid >> 5;
  const size_t base = ((size_t)(b * 8 + h) * TPB) * 32 + c;
  const int t0 = chunk * (NTOK / SCH);
  float m = -1e30f, s = 0.f;
  for (int i = sub; i < NTOK / SCH; i += 8) {
    float k = bf2f(kpl[base + (size_t)(t0 + i) * 32]);
    float nm = fmaxf(m, k);
    s = s * __expf(m - nm) + __expf(k - nm);
    m = nm;
  }
  __shared__ float sm[8][32], ss[8][32];
  sm[sub][c] = m; ss[sub][c] = s;
  __syncthreads();
  if (sub == 0) {
    for (int j = 1; j < 8; ++j) {
      float m2 = sm[j][c], s2 = ss[j][c];
      float nm = fmaxf(m, m2);
      s = s * __expf(m - nm) + s2 * __expf(m2 - nm);
      m = nm;
    }
    pm[bid * 32 + c] = m;
    ps[bid * 32 + c] = s;
  }
}

__global__ void kmerge(const float* __restrict__ pm, const float* __restrict__ ps,
                       float* __restrict__ lse) {
  int g = blockIdx.x * blockDim.x + threadIdx.x;
  if (g >= BATCH * 8 * 32) return;
  int c = g & 31, bh = g >> 5;
  float m = -1e30f, s = 0.f;
  for (int ch = 0; ch < SCH; ++ch) {
    int bid = bh * SCH + ch;
    float m2 = pm[bid * 32 + c], s2 = ps[bid * 32 + c];
    float nm = fmaxf(m, m2);
    s = s * __expf(m - nm) + s2 * __expf(m2 - nm);
    m = nm;
  }
  lse[g] = m + logf(s);
}

// ---------------- factor = ksoftmax^T @ V (split-K over tokens) -------------
__global__ __launch_bounds__(256)
void kfactor(const u16* __restrict__ kpl, const __half* __restrict__ vpl,
             const float* __restrict__ lse, float* __restrict__ fpart) {
  const int bid = blockIdx.x;               // (b*8+h)*FCH + chunk
  const int chunk = bid & (FCH - 1);
  const int h = (bid / FCH) & 7;
  const int b = bid / (FCH * 8);
  const int tid = threadIdx.x;
  const int c = tid & 31;
  const int d0 = (tid >> 5) * 4;
  const float lse_c = lse[(b * 8 + h) * 32 + c];
  __shared__ float wsm[64][32];
  __shared__ float vsm[64][32];              // unpadded: aligned b128 reads
  float a0 = 0.f, a1 = 0.f, a2 = 0.f, a3 = 0.f;
  const int t0 = chunk * (NTOK / FCH);
  for (int st = 0; st < (NTOK / FCH) / 64; ++st) {
    int tb = t0 + st * 64;
    const size_t base = ((size_t)(b * 8 + h) * TPB + tb) * 32;
#pragma unroll
    for (int i = 0; i < 8; ++i) {
      int flat = tid + i * 256;
      int tt = flat >> 5;
      int cc = flat & 31;
      wsm[tt][cc] = __expf(bf2f(kpl[base + flat]) - lse_c);
      vsm[tt][cc] = __half2float(vpl[base + flat]);
    }
    __syncthreads();
#pragma unroll 8
    for (int tt = 0; tt < 64; ++tt) {
      float w = wsm[tt][c];
      float4 vv = *(const float4*)&vsm[tt][d0];
      a0 += w * vv.x;
      a1 += w * vv.y;
      a2 += w * vv.z;
      a3 += w * vv.w;
    }
    __syncthreads();
  }
  float* fp = fpart + ((size_t)bid * 32 + c) * 32 + d0;
  fp[0] = a0; fp[1] = a1; fp[2] = a2; fp[3] = a3;
}

__global__ void fmerge(const float* __restrict__ fpart, float* __restrict__ factor) {
  int o = blockIdx.x * 256 + threadIdx.x;
  if (o >= BATCH * 8 * CHD * CHD) return;
  int cd = o & 1023, bh = o >> 10;
  float s = 0.f;
  for (int ch = 0; ch < FCH; ++ch)
    s += fpart[((size_t)(bh * FCH + ch) << 10) + cd];
  factor[o] = s;
}

// ---------------- patch: MFMA fa + register-row conv + assemble -------------
template <int K>
__global__ __launch_bounds__(256)
void kpatch3(const u16* __restrict__ qx, const __half* __restrict__ vpl,
             const float* __restrict__ factor,
             const float* __restrict__ wk, const float* __restrict__ bk,
             int h_base, int nh, u16* __restrict__ xout) {
  constexpr int HE = 16 + K - 1;
  constexpr int PADK = K / 2;
  constexpr int CSTRIDE = HE * 24 + 8;

  __shared__ u16 vt[32 * CSTRIDE];
  __shared__ u16 fa_s[256 * 32];
  __shared__ u16 FT[32 * 32];

  const int bid = blockIdx.x;
  const int tile = bid & 63;
  const int rem = bid >> 6;
  const int h = h_base + (rem % nh);
  const int b = rem / nh;
  const int y0 = (tile >> 3) * 16, x0 = (tile & 7) * 16;
  const int tid = threadIdx.x;
  const int btok = b * TPB;
  const size_t vbase = (size_t)(b * 8 + h) * TPB * 32;

  for (int flat = tid; flat < HE * HE * 8; flat += 256) {
    int pos = flat >> 3, c4 = (flat & 7) * 4;
    int y = pos / HE, xx_ = pos - y * HE;
    int yy = y0 + y - PADK, xx = x0 + xx_ - PADK;
    ushort4 v = make_ushort4(0, 0, 0, 0);
    if (yy >= 0 && yy < HH && xx >= 0 && xx < WW)
      v = *(const ushort4*)((const u16*)vpl + vbase + (size_t)(yy * WW + xx) * 32 + c4);
    vt[(c4 + 0) * CSTRIDE + y * 24 + xx_] = v.x;
    vt[(c4 + 1) * CSTRIDE + y * 24 + xx_] = v.y;
    vt[(c4 + 2) * CSTRIDE + y * 24 + xx_] = v.z;
    vt[(c4 + 3) * CSTRIDE + y * 24 + xx_] = v.w;
  }
  {
    int flat = tid;
    int d = flat >> 5, cc = flat & 31;
    FT[d * 32 + cc] = f2bf(factor[(size_t)((b * 8 + h) << 10) + cc * 32 + d]);
    flat = tid + 256; d = flat >> 5; cc = flat & 31;
    FT[d * 32 + cc] = f2bf(factor[(size_t)((b * 8 + h) << 10) + cc * 32 + d]);
    flat = tid + 512; d = flat >> 5; cc = flat & 31;
    FT[d * 32 + cc] = f2bf(factor[(size_t)((b * 8 + h) << 10) + cc * 32 + d]);
    flat = tid + 768; d = flat >> 5; cc = flat & 31;
    FT[d * 32 + cc] = f2bf(factor[(size_t)((b * 8 + h) << 10) + cc * 32 + d]);
  }
  __syncthreads();

  {
    const int lane = tid & 63;
    const int wid = tid >> 6;
    const int m16 = lane & 15;
    const int kg8 = (lane >> 4) * 8;
    bf16x8 bfr[2];
#pragma unroll
    for (int ni = 0; ni < 2; ++ni)
      bfr[ni] = *(const bf16x8*)&FT[(ni * 16 + m16) * 32 + kg8];
    f32x4 acc[4][2];
#pragma unroll
    for (int mi = 0; mi < 4; ++mi)
#pragma unroll
      for (int ni = 0; ni < 2; ++ni)
        acc[mi][ni] = (f32x4){0.f, 0.f, 0.f, 0.f};
#pragma unroll
    for (int mi = 0; mi < 4; ++mi) {
      int pos = wid * 64 + mi * 16 + m16;
      int token = (y0 + (pos >> 4)) * 128 + x0 + (pos & 15);
      bf16x8 af = *(const bf16x8*)(qx + (size_t)(btok + token) * 256 + h * 32 + kg8);
#pragma unroll
      for (int ni = 0; ni < 2; ++ni)
        acc[mi][ni] = __builtin_amdgcn_mfma_f32_16x16x32_bf16(
            af, bfr[ni], acc[mi][ni], 0, 0, 0);
    }
#pragma unroll
    for (int mi = 0; mi < 4; ++mi)
#pragma unroll
      for (int ni = 0; ni < 2; ++ni)
#pragma unroll
        for (int r = 0; r < 4; ++r) {
          int pos = wid * 64 + mi * 16 + (lane >> 4) * 4 + r;
          fa_s[pos * 32 + ni * 16 + m16] = f2bf(acc[mi][ni][r]);
        }
  }
  __syncthreads();

  const int c = tid & 31;
  const int syg = tid >> 5;
  const int widx = (h - h_base) * 32 + c;
  float wreg[K * K];
#pragma unroll
  for (int i = 0; i < K * K; ++i) wreg[i] = wk[widx * K * K + i];
  const float wb = bk[widx];

  float o[2][16];
#pragma unroll
  for (int ri = 0; ri < 2; ++ri)
#pragma unroll
    for (int p = 0; p < 16; ++p) o[ri][p] = 0.f;

#pragma unroll
  for (int ri = 0; ri < 2; ++ri) {
    const int yy = syg + ri * 8;
#pragma unroll
    for (int dy = 0; dy < K; ++dy) {
      const int vrow = yy + dy;
      union { uint4 q[3]; __half hh[24]; } row;
      row.q[0] = *(const uint4*)&vt[c * CSTRIDE + vrow * 24 + 0];
      row.q[1] = *(const uint4*)&vt[c * CSTRIDE + vrow * 24 + 8];
      row.q[2] = *(const uint4*)&vt[c * CSTRIDE + vrow * 24 + 16];
      float frow[HE];
#pragma unroll
      for (int j = 0; j < HE; ++j) frow[j] = __half2float(row.hh[j]);
#pragma unroll
      for (int dx = 0; dx < K; ++dx) {
        const float wv = wreg[dy * K + dx];
#pragma unroll
        for (int p = 0; p < 16; ++p)
          o[ri][p] += wv * frow[p + dx];
      }
    }
  }

#pragma unroll
  for (int ri = 0; ri < 2; ++ri) {
    const int yy = syg + ri * 8;
#pragma unroll
    for (int p = 0; p < 16; ++p) {
      const int pos = yy * 16 + p;
      const int token = (y0 + yy) * 128 + x0 + p;
      const size_t gidx = (size_t)(btok + token) * 256 + h * 32 + c;
      float fa = bf2f(fa_s[pos * 32 + c]);
      float qv = bf2f(qx[gidx]);
      xout[gidx] = f2bf(SCALE * fa + qv * (o[ri][p] + wb));
    }
  }
}

// ---------------- det branch ------------------------------------------------
__global__ __launch_bounds__(128)
void kdet(const u16* __restrict__ qx, const u16* __restrict__ kpl,
          const __half* __restrict__ vpl, u16* __restrict__ xout) {
  const int bid = blockIdx.x;   // b*8+h
  const int b = bid >> 3, h = bid & 7;
  const int tid = threadIdx.x;
  __shared__ float qd[100][32], kd[100][32], vd[100][32];
  __shared__ float pd[100][101];
  const size_t rq = ((size_t)b * TPB + NTOK) * CDIM;
  const size_t rp = ((size_t)(b * 8 + h) * TPB + NTOK) * 32;
  for (int flat = tid; flat < 100 * 32; flat += 128) {
    int t = flat >> 5, cc = flat & 31;
    qd[t][cc] = bf2f(qx[rq + (size_t)t * CDIM + h * CHD + cc]);
    kd[t][cc] = bf2f(kpl[rp + (size_t)t * 32 + cc]);
    vd[t][cc] = __half2float(vpl[rp + (size_t)t * 32 + cc]);
  }
  __syncthreads();
  const int r = tid;
  if (r < 100) {
    float mx = -1e30f;
    for (int j = 0; j < 100; ++j) {
      float s = 0.f;
#pragma unroll
      for (int cc = 0; cc < 32; ++cc) s += qd[r][cc] * kd[j][cc];
      s *= SCALE;
      pd[r][j] = s;
      mx = fmaxf(mx, s);
    }
    float sum = 0.f;
    for (int j = 0; j < 100; ++j) {
      float e = __expf(pd[r][j] - mx);
      pd[r][j] = e;
      sum += e;
    }
    float inv = 1.f / sum;
    for (int d = 0; d < 32; ++d) {
      float o = 0.f;
      for (int j = 0; j < 100; ++j) o += pd[r][j] * vd[j][d];
      xout[rq + (size_t)r * CDIM + h * CHD + d] = f2bf(o * inv);
    }
  }
}

// ---------------- launch ----------------------------------------------------
extern "C" void kernel_launch(void* const* d_in, const int* in_sizes, int n_in,
                              void* d_out, int out_size, void* d_ws, size_t ws_size,
                              hipStream_t stream) {
  if (ws_size < B_END) return;

  const float* x      = (const float*)d_in[0];
  const float* det    = (const float*)d_in[1];
  const float* qkv_w  = (const float*)d_in[4];
  const float* qkv_b  = (const float*)d_in[5];
  const float* proj_w = (const float*)d_in[6];
  const float* proj_b = (const float*)d_in[7];
  const float* w3     = (const float*)d_in[8];
  const float* b3     = (const float*)d_in[9];
  const float* w5     = (const float*)d_in[10];
  const float* b5     = (const float*)d_in[11];
  const float* w7     = (const float*)d_in[12];
  const float* b7     = (const float*)d_in[13];

  char* wsb = (char*)d_ws;
  u16* qx      = (u16*)(wsb + B_QX);
  u16* kpl     = (u16*)(wsb + B_KPL);
  __half* vpl  = (__half*)(wsb + B_VPL);
  u16* WqT     = (u16*)(wsb + B_WQT);
  u16* WpT     = (u16*)(wsb + B_WPT);
  float* pm    = (float*)(wsb + B_PM);
  float* ps    = (float*)(wsb + B_PS);
  float* fpart = (float*)(wsb + B_FPART);
  float* factor= (float*)(wsb + B_FACTOR);
  float* lse   = (float*)(wsb + B_LSE);
  float* out   = (float*)d_out;
  u16* xbf     = (u16*)d_out;     // scratch alias; overwritten by gemm_proj

  prep<<<4096, 256, 0, stream>>>(x, det, qkv_w, proj_w, xbf, WqT, WpT);

  gemm_qkv<<<3120, 256, 0, stream>>>(xbf, WqT, qkv_b, qx, kpl, vpl);

  kstats<<<BATCH * 8 * SCH, 256, 0, stream>>>(kpl, pm, ps);
  kmerge<<<4, 256, 0, stream>>>(pm, ps, lse);
  kfactor<<<BATCH * 8 * FCH, 256, 0, stream>>>(kpl, vpl, lse, fpart);
  fmerge<<<128, 256, 0, stream>>>(fpart, factor);

  kpatch3<3><<<BATCH * 2 * 64, 256, 0, stream>>>(qx, vpl, factor, w3, b3, 0, 2, qx);
  kpatch3<5><<<BATCH * 3 * 64, 256, 0, stream>>>(qx, vpl, factor, w5, b5, 2, 3, qx);
  kpatch3<7><<<BATCH * 3 * 64, 256, 0, stream>>>(qx, vpl, factor, w7, b7, 5, 3, qx);

  kdet<<<BATCH * 8, 128, 0, stream>>>(qx, kpl, vpl, qx);

  dim3 g2((ROWS + 127) / 128, CDIM / 128);
  gemm_proj<<<g2, 256, 0, stream>>>(qx, WpT, proj_b, out);
}